// Round 11
// baseline (318.870 us; speedup 1.0000x reference)
//
#include <hip/hip_runtime.h>

typedef __bf16 bf8 __attribute__((ext_vector_type(8)));
typedef float f4 __attribute__((ext_vector_type(4)));
typedef _Float16 h8 __attribute__((ext_vector_type(8)));

// Problem constants (fixed by reference)
constexpr int BSZ = 2, NSEQ = 2048, DIM = 512, NH = 8, DH = 64, INNER = 512;
constexpr int ROWS = BSZ * NSEQ;          // 4096

// Workspace layout (bytes)
constexpr size_t XB_OFF  = 0;                          // x cast bf16: 4096*512*2 = 4 MB
constexpr size_t WQT_OFF = 4194304;                    // W_qkv^T bf16 [1536][512] = 1.5 MB
constexpr size_t WOT_OFF = WQT_OFF + 1572864;          // W_out^T bf16 [512][512] = 0.5 MB
constexpr size_t Q_OFF   = WOT_OFF + 524288;           // Q/8 bf16 [2][8][2048][64] = 4 MB
constexpr size_t K_OFF   = Q_OFF + 4194304;            // K bf16 = 4 MB
constexpr size_t V_OFF   = K_OFF + 4194304;            // V bf16 = 4 MB
constexpr size_t AO_OFF  = V_OFF + 4194304;            // attn out bf16 [4096][512] = 4 MB

// ---------------- prep: cast x to bf16; transpose+cast W_qkv, W_out ----------------
__global__ __launch_bounds__(256) void prep_kernel(
    const float* __restrict__ x, const float* __restrict__ Wq, const float* __restrict__ Wo,
    __bf16* __restrict__ xb, __bf16* __restrict__ wqt, __bf16* __restrict__ wot) {
  int idx = blockIdx.x * 256 + threadIdx.x;
  if (idx < ROWS * DIM) xb[idx] = (__bf16)x[idx];
  if (idx < 3 * INNER * DIM) {            // wqt[n][k] = Wq[k][n],  n<1536, k<512
    int n = idx >> 9, k = idx & 511;
    wqt[idx] = (__bf16)Wq[k * (3 * INNER) + n];
  }
  if (idx < INNER * DIM) {                // wot[n][k] = Wo[k][n]
    int n = idx >> 9, k = idx & 511;
    wot[idx] = (__bf16)Wo[k * DIM + n];
  }
}

// ---------------- kernel 1: qkv = x @ W_qkv, scatter into per-head Q/8, K, V ----------------
__global__ __launch_bounds__(256) void qkv_gemm(
    const __bf16* __restrict__ xb, const __bf16* __restrict__ wqt,
    __bf16* __restrict__ Qh, __bf16* __restrict__ Kh, __bf16* __restrict__ Vh) {
  int bid = blockIdx.x;
  int bn = bid % 24, bm = bid / 24;           // 24 col-tiles of 64, 64 row-tiles of 64
  int lane = threadIdx.x & 63, wid = threadIdx.x >> 6;
  int r0 = bm * 64 + wid * 16;
  const __bf16* ap = xb  + (size_t)(r0 + (lane & 15)) * 512 + ((lane >> 4) * 8);
  const __bf16* bp = wqt + (size_t)(bn * 64 + (lane & 15)) * 512 + ((lane >> 4) * 8);
  f4 acc[4] = {{0.f,0.f,0.f,0.f},{0.f,0.f,0.f,0.f},{0.f,0.f,0.f,0.f},{0.f,0.f,0.f,0.f}};
#pragma unroll
  for (int kk = 0; kk < 16; ++kk) {
    bf8 a = *(const bf8*)(ap + kk * 32);
#pragma unroll
    for (int jt = 0; jt < 4; ++jt) {
      bf8 b = *(const bf8*)(bp + jt * 16 * 512 + kk * 32);
      acc[jt] = __builtin_amdgcn_mfma_f32_16x16x32_bf16(a, b, acc[jt], 0, 0, 0);
    }
  }
#pragma unroll
  for (int jt = 0; jt < 4; ++jt) {
    int col = bn * 64 + jt * 16 + (lane & 15);
    int which = col >> 9;                    // 0=q 1=k 2=v
    int inner = col & 511;
    int h = inner >> 6, d = inner & 63;
    __bf16* dst = which == 0 ? Qh : (which == 1 ? Kh : Vh);
    float scale = which == 0 ? 0.125f : 1.0f;  // fold SCALE=1/8 into Q (exact)
#pragma unroll
    for (int i = 0; i < 4; ++i) {
      int row = r0 + (lane >> 4) * 4 + i;
      int b = row >> 11, n = row & 2047;
      dst[(((size_t)(b * 8 + h)) * 2048 + n) * 64 + d] = (__bf16)(acc[jt][i] * scale);
    }
  }
}

// ---------------- kernel 2: sparsemax attention (template: DIAG=0 real, 1/2 ablations) ----
// f16 scores (64KB) + 8KB cand lists -> 72KB LDS -> 2 blocks/CU (full 8 waves/SIMD).
template<int DIAG>
__global__ __launch_bounds__(1024, 8) void attn_kernel_t(
    const __bf16* __restrict__ Qh, const __bf16* __restrict__ Kh,
    const __bf16* __restrict__ Vh, __bf16* __restrict__ AO, float* __restrict__ dg) {
  __shared__ _Float16 S[16 * 2048];         // 64 KB, XOR-swizzled (col ^= (row&12)<<2)
  __shared__ float candv[16][64];           // 4 KB
  __shared__ int   candj[16][64];           // 4 KB
  int bid = blockIdx.x;
  int lin = (bid & 7) * 256 + (bid >> 3);   // XCD-aware swizzle (2048 % 8 == 0, bijective)
  int bh = lin >> 7;                        // 0..15 = b*8+h
  int qt = lin & 127;                       // q-tile within head
  int lane = threadIdx.x & 63, wid = threadIdx.x >> 6;   // 16 waves
  int n0 = qt * 16;
  const __bf16* Qp = Qh + ((size_t)bh * 2048 + n0) * 64;
  const __bf16* Kp = Kh + (size_t)bh * 2048 * 64;
  const __bf16* Vp = Vh + (size_t)bh * 2048 * 64;
  int koff = (lane >> 4) * 8;

  // ---- phase 1: S[16][2048] = (Q/8) @ K^T, f16 into LDS ----
  bf8 a0 = *(const bf8*)(Qp + (lane & 15) * 64 + koff);
  bf8 a1 = *(const bf8*)(Qp + (lane & 15) * 64 + 32 + koff);
  float psum = 0.f;                         // DIAG2 keepalive
#pragma unroll
  for (int t = 0; t < 8; ++t) {
    int jt = wid * 8 + t;                   // 128 col-tiles over 16 waves
    const __bf16* kb = Kp + (size_t)(jt * 16 + (lane & 15)) * 64 + koff;
    bf8 b0 = *(const bf8*)(kb);
    bf8 b1 = *(const bf8*)(kb + 32);
    f4 acc = {0.f, 0.f, 0.f, 0.f};
    acc = __builtin_amdgcn_mfma_f32_16x16x32_bf16(a0, b0, acc, 0, 0, 0);
    acc = __builtin_amdgcn_mfma_f32_16x16x32_bf16(a1, b1, acc, 0, 0, 0);
    if constexpr (DIAG == 2) {
      psum += acc[0] + acc[1] + acc[2] + acc[3];
    } else {
#pragma unroll
      for (int i = 0; i < 4; ++i) {
        int row = (lane >> 4) * 4 + i;      // C layout: col=lane&15, row=(lane>>4)*4+i
        int col = jt * 16 + (lane & 15);
        S[row * 2048 + (col ^ ((row & 12) << 2))] = (_Float16)acc[i];
      }
    }
  }
  if constexpr (DIAG == 2) {                // loads+MFMA only: keep acc live, done
    if (psum == 1234.5678f) dg[0] = psum + (float)S[0];
    return;
  }
  __syncthreads();
  if constexpr (DIAG == 1) {                // phase-1-only: S-dependent read, done
    float v = (float)S[threadIdx.x * 32];
    if (v == 1234.5678f) dg[0] = v;
    return;
  }

  // ---- phase 2: one wave per q-row ----
  int row = wid;
  int swz = (row & 12) << 2;
  const _Float16* Srow = S + row * 2048;
  h8 zc[4];
#pragma unroll
  for (int r = 0; r < 4; ++r)
    zc[r] = *(const h8*)&Srow[(r * 512 + lane * 8) ^ swz];

  // row max (butterfly leaves identical value in all lanes)
  float mx = -1e30f;
#pragma unroll
  for (int r = 0; r < 4; ++r)
#pragma unroll
    for (int i = 0; i < 8; ++i) mx = fmaxf(mx, (float)zc[r][i]);
#pragma unroll
  for (int o = 32; o; o >>= 1) mx = fmaxf(mx, __shfl_xor(mx, o));

  // tau* >= max-1 (p_max <= 1), so z <= max-1 is provably outside the support.
  float tau0 = mx - 1.0f;
  // prefill this wave's cand row so unwritten slots are inert
  candv[row][lane] = -1e30f;
  candj[row][lane] = 0;
  unsigned mask = 0;
#pragma unroll
  for (int r = 0; r < 4; ++r)
#pragma unroll
    for (int i = 0; i < 8; ++i)
      if ((float)zc[r][i] > tau0) mask |= 1u << (r * 8 + i);
  int pc = __popc(mask);
  int off = pc;                             // inclusive prefix-scan over 64 lanes
#pragma unroll
  for (int d = 1; d < 64; d <<= 1) {
    int t = __shfl_up(off, d);
    if (lane >= d) off += t;
  }
  int total = __shfl(off, 63);              // candidates in this row (wave-uniform)
  off -= pc;                                // exclusive

  float tau = tau0, acc_o = 0.f;
  if (total <= 64) {
    // compact candidates to LDS (wave-private row; no barrier needed)
    int slot = off;
#pragma unroll
    for (int r = 0; r < 4; ++r)
#pragma unroll
      for (int i = 0; i < 8; ++i)
        if (mask & (1u << (r * 8 + i))) {
          candv[row][slot] = (float)zc[r][i];
          candj[row][slot] = r * 512 + lane * 8 + i;
          ++slot;
        }
    if (total <= 16) {
      // register path: 4 broadcast b128 loads, then pure-VALU Michelot (no cross-lane)
      f4 cv0 = *(const f4*)&candv[row][0];
      f4 cv1 = *(const f4*)&candv[row][4];
      f4 cv2 = *(const f4*)&candv[row][8];
      f4 cv3 = *(const f4*)&candv[row][12];
      float cprev = -1.0f;
      for (int it = 0; it < 20; ++it) {
        float s = 0.f, c = 0.f;
#pragma unroll
        for (int i = 0; i < 4; ++i) {
          if (cv0[i] > tau) { s += cv0[i]; c += 1.f; }
          if (cv1[i] > tau) { s += cv1[i]; c += 1.f; }
          if (cv2[i] > tau) { s += cv2[i]; c += 1.f; }
          if (cv3[i] > tau) { s += cv3[i]; c += 1.f; }
        }
        if (c == cprev) break;
        tau = (s - 1.0f) / c; cprev = c;
      }
      // branchless pipelined gather: dead slots have p<=0 -> contribute exactly 0
      const __bf16* vb = Vp + lane;
#pragma unroll
      for (int jc = 0; jc < 4; ++jc) {
        f4 cj = jc == 0 ? cv0 : (jc == 1 ? cv1 : (jc == 2 ? cv2 : cv3));
        int j0 = candj[row][jc * 4 + 0];
        int j1 = candj[row][jc * 4 + 1];
        int j2 = candj[row][jc * 4 + 2];
        int j3 = candj[row][jc * 4 + 3];
        acc_o += fmaxf(cj[0] - tau, 0.f) * (float)vb[(size_t)j0 * 64];
        acc_o += fmaxf(cj[1] - tau, 0.f) * (float)vb[(size_t)j1 * 64];
        acc_o += fmaxf(cj[2] - tau, 0.f) * (float)vb[(size_t)j2 * 64];
        acc_o += fmaxf(cj[3] - tau, 0.f) * (float)vb[(size_t)j3 * 64];
      }
    } else {
      // mid path: Michelot on 1 candidate per lane (butterfly reduce)
      float v = candv[row][lane];
      bool valid = lane < total;
      float cprev = -1.0f;
      for (int it = 0; it < 24; ++it) {
        bool in = valid && (v > tau);
        float s = in ? v : 0.f, c = in ? 1.f : 0.f;
#pragma unroll
        for (int o = 32; o; o >>= 1) { s += __shfl_xor(s, o); c += __shfl_xor(c, o); }
        if (c == cprev) break;
        tau = (s - 1.0f) / c; cprev = c;
      }
      for (int j = 0; j < total; ++j) {
        float p = candv[row][j] - tau;
        if (p > 0.f) {                      // wave-uniform branch
          int idx = candj[row][j];
          acc_o += p * (float)Vp[(size_t)idx * 64 + lane];
        }
      }
    }
  } else {
    // fallback (rare): full-register Michelot from tau0 + ballot gather
    float cprev = -1.0f;
    for (int it = 0; it < 48; ++it) {
      float s = 0.f, c = 0.f;
#pragma unroll
      for (int r = 0; r < 4; ++r)
#pragma unroll
        for (int i = 0; i < 8; ++i) {
          float zz = (float)zc[r][i];
          if (zz > tau) { s += zz; c += 1.f; }
        }
#pragma unroll
      for (int o = 32; o; o >>= 1) { s += __shfl_xor(s, o); c += __shfl_xor(c, o); }
      if (c == cprev) break;
      tau = (s - 1.0f) / c; cprev = c;
    }
#pragma unroll
    for (int r = 0; r < 4; ++r)
#pragma unroll
      for (int i = 0; i < 8; ++i) {
        float p = (float)zc[r][i] - tau;
        unsigned long long m = __ballot(p > 0.f);
        while (m) {
          int src = __ffsll((long long)m) - 1;
          m &= m - 1;
          float pj = __shfl(p, src);
          int j = r * 512 + src * 8 + i;
          acc_o += pj * (float)Vp[(size_t)j * 64 + lane];
        }
      }
  }
  int rowg = (bh >> 3) * 2048 + n0 + row;   // [B][N] row
  AO[(size_t)rowg * 512 + (bh & 7) * 64 + lane] = (__bf16)acc_o;
}

// ---------------- kernel 3: out = AO @ W_out + b_out (f32 result) ----------------
__global__ __launch_bounds__(256) void out_gemm(
    const __bf16* __restrict__ A, const __bf16* __restrict__ wot,
    const float* __restrict__ bias, float* __restrict__ out) {
  int bid = blockIdx.x;
  int bn = bid & 7, bm = bid >> 3;          // 8 col-tiles of 64, 64 row-tiles
  int lane = threadIdx.x & 63, wid = threadIdx.x >> 6;
  int r0 = bm * 64 + wid * 16;
  const __bf16* ap = A   + (size_t)(r0 + (lane & 15)) * 512 + ((lane >> 4) * 8);
  const __bf16* bp = wot + (size_t)(bn * 64 + (lane & 15)) * 512 + ((lane >> 4) * 8);
  f4 acc[4] = {{0.f,0.f,0.f,0.f},{0.f,0.f,0.f,0.f},{0.f,0.f,0.f,0.f},{0.f,0.f,0.f,0.f}};
#pragma unroll
  for (int kk = 0; kk < 16; ++kk) {
    bf8 a = *(const bf8*)(ap + kk * 32);
#pragma unroll
    for (int jt = 0; jt < 4; ++jt) {
      bf8 b = *(const bf8*)(bp + jt * 16 * 512 + kk * 32);
      acc[jt] = __builtin_amdgcn_mfma_f32_16x16x32_bf16(a, b, acc[jt], 0, 0, 0);
    }
  }
#pragma unroll
  for (int jt = 0; jt < 4; ++jt) {
    int col = bn * 64 + jt * 16 + (lane & 15);
    float bv = bias[col];
#pragma unroll
    for (int i = 0; i < 4; ++i) {
      int row = r0 + (lane >> 4) * 4 + i;
      out[(size_t)row * 512 + col] = acc[jt][i] + bv;
    }
  }
}

extern "C" void kernel_launch(void* const* d_in, const int* in_sizes, int n_in,
                              void* d_out, int out_size, void* d_ws, size_t ws_size,
                              hipStream_t stream) {
  const float* x  = (const float*)d_in[0];
  const float* Wq = (const float*)d_in[1];
  const float* Wo = (const float*)d_in[2];
  const float* bo = (const float*)d_in[3];
  char* ws = (char*)d_ws;
  __bf16* xb  = (__bf16*)(ws + XB_OFF);
  __bf16* wqt = (__bf16*)(ws + WQT_OFF);
  __bf16* wot = (__bf16*)(ws + WOT_OFF);
  __bf16* Qh  = (__bf16*)(ws + Q_OFF);
  __bf16* Kh  = (__bf16*)(ws + K_OFF);
  __bf16* Vh  = (__bf16*)(ws + V_OFF);
  __bf16* AO  = (__bf16*)(ws + AO_OFF);
  float*  dgs = (float*)(ws + XB_OFF);      // diag scratch: xb is dead after qkv_gemm

  prep_kernel<<<(ROWS * DIM) / 256, 256, 0, stream>>>(x, Wq, Wo, xb, wqt, wot);
  qkv_gemm<<<(ROWS / 64) * (3 * INNER / 64), 256, 0, stream>>>(xb, wqt, Qh, Kh, Vh);
  attn_kernel_t<0><<<16 * (NSEQ / 16), 1024, 0, stream>>>(Qh, Kh, Vh, AO, dgs);
  // diagnostics (write only to dead scratch; xb is fully rewritten by prep next call)
  attn_kernel_t<1><<<16 * (NSEQ / 16), 1024, 0, stream>>>(Qh, Kh, Vh, AO, dgs);
  attn_kernel_t<2><<<16 * (NSEQ / 16), 1024, 0, stream>>>(Qh, Kh, Vh, AO, dgs);
  out_gemm<<<(ROWS / 64) * (INNER / 64), 256, 0, stream>>>(AO, wot, bo, (float*)d_out);
}

// Round 13
// 231.847 us; speedup vs baseline: 1.3753x; 1.3753x over previous
//
#include <hip/hip_runtime.h>

typedef __bf16 bf8 __attribute__((ext_vector_type(8)));
typedef float f4 __attribute__((ext_vector_type(4)));
typedef _Float16 h8 __attribute__((ext_vector_type(8)));

// Problem constants (fixed by reference)
constexpr int BSZ = 2, NSEQ = 2048, DIM = 512, NH = 8, DH = 64, INNER = 512;
constexpr int ROWS = BSZ * NSEQ;          // 4096

// Workspace layout (bytes)
constexpr size_t XB_OFF  = 0;                          // x cast bf16: 4 MB
constexpr size_t WQT_OFF = 4194304;                    // W_qkv^T bf16: 1.5 MB
constexpr size_t WOT_OFF = WQT_OFF + 1572864;          // W_out^T bf16: 0.5 MB
constexpr size_t Q_OFF   = WOT_OFF + 524288;           // Q/8 bf16 [16][2048][64]: 4 MB
constexpr size_t K_OFF   = Q_OFF + 4194304;            // K bf16: 4 MB
constexpr size_t V_OFF   = K_OFF + 4194304;            // V bf16: 4 MB
constexpr size_t AO_OFF  = V_OFF + 4194304;            // attn out bf16 [4096][512]: 4 MB
constexpr size_t SG_OFF  = AO_OFF + 4194304;           // S chunk f16 [4][2048][2048]: 32 MB
// total 54 MB

// ---------------- prep: cast x to bf16; transpose+cast W_qkv, W_out ----------------
__global__ __launch_bounds__(256) void prep_kernel(
    const float* __restrict__ x, const float* __restrict__ Wq, const float* __restrict__ Wo,
    __bf16* __restrict__ xb, __bf16* __restrict__ wqt, __bf16* __restrict__ wot) {
  int idx = blockIdx.x * 256 + threadIdx.x;
  if (idx < ROWS * DIM) xb[idx] = (__bf16)x[idx];
  if (idx < 3 * INNER * DIM) {            // wqt[n][k] = Wq[k][n]
    int n = idx >> 9, k = idx & 511;
    wqt[idx] = (__bf16)Wq[k * (3 * INNER) + n];
  }
  if (idx < INNER * DIM) {                // wot[n][k] = Wo[k][n]
    int n = idx >> 9, k = idx & 511;
    wot[idx] = (__bf16)Wo[k * DIM + n];
  }
}

// ---------------- kernel 1: qkv = x @ W_qkv, scatter into per-head Q/8, K, V ----------------
__global__ __launch_bounds__(256) void qkv_gemm(
    const __bf16* __restrict__ xb, const __bf16* __restrict__ wqt,
    __bf16* __restrict__ Qh, __bf16* __restrict__ Kh, __bf16* __restrict__ Vh) {
  int bid = blockIdx.x;
  int bn = bid % 24, bm = bid / 24;
  int lane = threadIdx.x & 63, wid = threadIdx.x >> 6;
  int r0 = bm * 64 + wid * 16;
  const __bf16* ap = xb  + (size_t)(r0 + (lane & 15)) * 512 + ((lane >> 4) * 8);
  const __bf16* bp = wqt + (size_t)(bn * 64 + (lane & 15)) * 512 + ((lane >> 4) * 8);
  f4 acc[4] = {{0.f,0.f,0.f,0.f},{0.f,0.f,0.f,0.f},{0.f,0.f,0.f,0.f},{0.f,0.f,0.f,0.f}};
#pragma unroll
  for (int kk = 0; kk < 16; ++kk) {
    bf8 a = *(const bf8*)(ap + kk * 32);
#pragma unroll
    for (int jt = 0; jt < 4; ++jt) {
      bf8 b = *(const bf8*)(bp + jt * 16 * 512 + kk * 32);
      acc[jt] = __builtin_amdgcn_mfma_f32_16x16x32_bf16(a, b, acc[jt], 0, 0, 0);
    }
  }
#pragma unroll
  for (int jt = 0; jt < 4; ++jt) {
    int col = bn * 64 + jt * 16 + (lane & 15);
    int which = col >> 9;                    // 0=q 1=k 2=v
    int inner = col & 511;
    int h = inner >> 6, d = inner & 63;
    __bf16* dst = which == 0 ? Qh : (which == 1 ? Kh : Vh);
    float scale = which == 0 ? 0.125f : 1.0f;  // fold SCALE=1/8 into Q (exact)
#pragma unroll
    for (int i = 0; i < 4; ++i) {
      int row = r0 + (lane >> 4) * 4 + i;
      int b = row >> 11, n = row & 2047;
      dst[(((size_t)(b * 8 + h)) * 2048 + n) * 64 + d] = (__bf16)(acc[jt][i] * scale);
    }
  }
}

// ---------------- kernel 2a: S = (Q/8) @ K^T for 4 heads, 128x128 tiles -> global f16 ----
// 4 waves x 32-row strips; epilogue via XOR-swizzled wave-private LDS -> coalesced stores.
__global__ __launch_bounds__(256, 4) void qk_gemm(
    const __bf16* __restrict__ Qh, const __bf16* __restrict__ Kh,
    _Float16* __restrict__ Sg, int bh0) {
  __shared__ _Float16 ct[4][32][128];       // 32 KB, col ^ (((row>>2)&3)<<4)
  int bid = blockIdx.x;
  int hh = bid >> 8;                        // 0..3 head within chunk
  int rt = (bid >> 4) & 15;                 // q row-tile (128)
  int colt = bid & 15;                      // k col-tile (128)
  int lane = threadIdx.x & 63, wid = threadIdx.x >> 6;
  int bh = bh0 + hh;
  int l15 = lane & 15, koff = (lane >> 4) * 8;
  const __bf16* Qp = Qh + ((size_t)bh * 2048 + rt * 128 + wid * 32) * 64;
  const __bf16* Kp = Kh + ((size_t)bh * 2048 + colt * 128) * 64;

  bf8 aA0 = *(const bf8*)(Qp + l15 * 64 + koff);
  bf8 aA1 = *(const bf8*)(Qp + l15 * 64 + 32 + koff);
  bf8 aB0 = *(const bf8*)(Qp + (16 + l15) * 64 + koff);
  bf8 aB1 = *(const bf8*)(Qp + (16 + l15) * 64 + 32 + koff);
  f4 acc[2][8];
#pragma unroll
  for (int s = 0; s < 2; ++s)
#pragma unroll
    for (int j = 0; j < 8; ++j) acc[s][j] = (f4){0.f, 0.f, 0.f, 0.f};
#pragma unroll
  for (int ctj = 0; ctj < 8; ++ctj) {
    const __bf16* kb = Kp + (size_t)(ctj * 16 + l15) * 64 + koff;
    bf8 b0 = *(const bf8*)(kb);
    bf8 b1 = *(const bf8*)(kb + 32);
    acc[0][ctj] = __builtin_amdgcn_mfma_f32_16x16x32_bf16(aA0, b0, acc[0][ctj], 0, 0, 0);
    acc[0][ctj] = __builtin_amdgcn_mfma_f32_16x16x32_bf16(aA1, b1, acc[0][ctj], 0, 0, 0);
    acc[1][ctj] = __builtin_amdgcn_mfma_f32_16x16x32_bf16(aB0, b0, acc[1][ctj], 0, 0, 0);
    acc[1][ctj] = __builtin_amdgcn_mfma_f32_16x16x32_bf16(aB1, b1, acc[1][ctj], 0, 0, 0);
  }
  // repack to wave-private LDS (XOR-swizzled: conflict-free b16 writes, aligned b128 reads)
#pragma unroll
  for (int s = 0; s < 2; ++s)
#pragma unroll
    for (int ctj = 0; ctj < 8; ++ctj)
#pragma unroll
      for (int i = 0; i < 4; ++i) {
        int row = s * 16 + (lane >> 4) * 4 + i;
        int col = ctj * 16 + l15;
        ct[wid][row][col ^ (((row >> 2) & 3) << 4)] = (_Float16)acc[s][ctj][i];
      }
  // coalesced store: per iter, 4 rows x 16 chunks of 16B = full 128-col rows
  int r4 = lane >> 4, ch = lane & 15;       // FIX(R12): was lane>>3/lane&7 -> only half
  size_t srow0 = (size_t)hh * 2048 + rt * 128 + wid * 32;   //   the columns were stored
#pragma unroll
  for (int it = 0; it < 8; ++it) {
    int r = it * 4 + r4;
    h8 v = *(const h8*)&ct[wid][r][(ch * 8) ^ (((r >> 2) & 3) << 4)];
    *(h8*)&Sg[(srow0 + r) * 2048 + colt * 128 + ch * 8] = v;
  }
}

// ---------------- kernel 2b: sparsemax + sparse PV, one wave per q-row ----------------
__global__ __launch_bounds__(512, 8) void sparse_pv(
    const _Float16* __restrict__ Sg, const __bf16* __restrict__ Vh,
    __bf16* __restrict__ AO, int bh0) {
  __shared__ float candv[8][64];            // 2 KB
  __shared__ int   candj[8][64];            // 2 KB
  int lane = threadIdx.x & 63, wid = threadIdx.x >> 6;   // 8 waves
  int rowid = blockIdx.x * 8 + wid;         // 0..8191 within chunk
  int hh = rowid >> 11, n = rowid & 2047;
  int bh = bh0 + hh;
  const _Float16* Srow = Sg + ((size_t)hh * 2048 + n) * 2048;
  const __bf16* Vp = Vh + (size_t)bh * 2048 * 64;

  h8 zc[4];
#pragma unroll
  for (int r = 0; r < 4; ++r)
    zc[r] = *(const h8*)&Srow[r * 512 + lane * 8];

  // row max (butterfly leaves identical value in all lanes)
  float mx = -1e30f;
#pragma unroll
  for (int r = 0; r < 4; ++r)
#pragma unroll
    for (int i = 0; i < 8; ++i) mx = fmaxf(mx, (float)zc[r][i]);
#pragma unroll
  for (int o = 32; o; o >>= 1) mx = fmaxf(mx, __shfl_xor(mx, o));

  // tau* >= max-1 (p_max <= 1): z <= max-1 is provably outside the support.
  float tau0 = mx - 1.0f;
  candv[wid][lane] = -1e30f;                // prefill so unwritten slots are inert
  candj[wid][lane] = 0;
  unsigned mask = 0;
#pragma unroll
  for (int r = 0; r < 4; ++r)
#pragma unroll
    for (int i = 0; i < 8; ++i)
      if ((float)zc[r][i] > tau0) mask |= 1u << (r * 8 + i);
  int pc = __popc(mask);
  int off = pc;                             // inclusive prefix-scan over 64 lanes
#pragma unroll
  for (int d = 1; d < 64; d <<= 1) {
    int t = __shfl_up(off, d);
    if (lane >= d) off += t;
  }
  int total = __shfl(off, 63);              // wave-uniform candidate count
  off -= pc;                                // exclusive

  float tau = tau0, acc_o = 0.f;
  if (total <= 64) {
    int slot = off;
#pragma unroll
    for (int r = 0; r < 4; ++r)
#pragma unroll
      for (int i = 0; i < 8; ++i)
        if (mask & (1u << (r * 8 + i))) {
          candv[wid][slot] = (float)zc[r][i];
          candj[wid][slot] = r * 512 + lane * 8 + i;
          ++slot;
        }
    if (total <= 16) {
      // register path: 4 broadcast b128 loads, pure-VALU Michelot, branchless gather
      f4 cv0 = *(const f4*)&candv[wid][0];
      f4 cv1 = *(const f4*)&candv[wid][4];
      f4 cv2 = *(const f4*)&candv[wid][8];
      f4 cv3 = *(const f4*)&candv[wid][12];
      float cprev = -1.0f;
      for (int it = 0; it < 20; ++it) {
        float s = 0.f, c = 0.f;
#pragma unroll
        for (int i = 0; i < 4; ++i) {
          if (cv0[i] > tau) { s += cv0[i]; c += 1.f; }
          if (cv1[i] > tau) { s += cv1[i]; c += 1.f; }
          if (cv2[i] > tau) { s += cv2[i]; c += 1.f; }
          if (cv3[i] > tau) { s += cv3[i]; c += 1.f; }
        }
        if (c == cprev) break;
        tau = (s - 1.0f) / c; cprev = c;
      }
      const __bf16* vb = Vp + lane;
#pragma unroll
      for (int jc = 0; jc < 4; ++jc) {
        f4 cj = jc == 0 ? cv0 : (jc == 1 ? cv1 : (jc == 2 ? cv2 : cv3));
        int j0 = candj[wid][jc * 4 + 0];
        int j1 = candj[wid][jc * 4 + 1];
        int j2 = candj[wid][jc * 4 + 2];
        int j3 = candj[wid][jc * 4 + 3];
        acc_o += fmaxf(cj[0] - tau, 0.f) * (float)vb[(size_t)j0 * 64];
        acc_o += fmaxf(cj[1] - tau, 0.f) * (float)vb[(size_t)j1 * 64];
        acc_o += fmaxf(cj[2] - tau, 0.f) * (float)vb[(size_t)j2 * 64];
        acc_o += fmaxf(cj[3] - tau, 0.f) * (float)vb[(size_t)j3 * 64];
      }
    } else {
      // mid path: Michelot on 1 candidate per lane (butterfly reduce)
      float v = candv[wid][lane];
      bool valid = lane < total;
      float cprev = -1.0f;
      for (int it = 0; it < 24; ++it) {
        bool in = valid && (v > tau);
        float s = in ? v : 0.f, c = in ? 1.f : 0.f;
#pragma unroll
        for (int o = 32; o; o >>= 1) { s += __shfl_xor(s, o); c += __shfl_xor(c, o); }
        if (c == cprev) break;
        tau = (s - 1.0f) / c; cprev = c;
      }
      for (int j = 0; j < total; ++j) {
        float p = candv[wid][j] - tau;
        if (p > 0.f) {
          int idx = candj[wid][j];
          acc_o += p * (float)Vp[(size_t)idx * 64 + lane];
        }
      }
    }
  } else {
    // fallback (rare): full-register Michelot from tau0 + ballot gather
    float cprev = -1.0f;
    for (int it = 0; it < 48; ++it) {
      float s = 0.f, c = 0.f;
#pragma unroll
      for (int r = 0; r < 4; ++r)
#pragma unroll
        for (int i = 0; i < 8; ++i) {
          float zz = (float)zc[r][i];
          if (zz > tau) { s += zz; c += 1.f; }
        }
#pragma unroll
      for (int o = 32; o; o >>= 1) { s += __shfl_xor(s, o); c += __shfl_xor(c, o); }
      if (c == cprev) break;
      tau = (s - 1.0f) / c; cprev = c;
    }
#pragma unroll
    for (int r = 0; r < 4; ++r)
#pragma unroll
      for (int i = 0; i < 8; ++i) {
        float p = (float)zc[r][i] - tau;
        unsigned long long m = __ballot(p > 0.f);
        while (m) {
          int src = __ffsll((long long)m) - 1;
          m &= m - 1;
          float pj = __shfl(p, src);
          int j = r * 512 + src * 8 + i;
          acc_o += pj * (float)Vp[(size_t)j * 64 + lane];
        }
      }
  }
  int rowg = (bh >> 3) * 2048 + n;          // [B][N] row
  AO[(size_t)rowg * 512 + (bh & 7) * 64 + lane] = (__bf16)acc_o;
}

// ---------------- kernel 3: out = AO @ W_out + b_out (f32 result) ----------------
__global__ __launch_bounds__(256) void out_gemm(
    const __bf16* __restrict__ A, const __bf16* __restrict__ wot,
    const float* __restrict__ bias, float* __restrict__ out) {
  int bid = blockIdx.x;
  int bn = bid & 7, bm = bid >> 3;
  int lane = threadIdx.x & 63, wid = threadIdx.x >> 6;
  int r0 = bm * 64 + wid * 16;
  const __bf16* ap = A   + (size_t)(r0 + (lane & 15)) * 512 + ((lane >> 4) * 8);
  const __bf16* bp = wot + (size_t)(bn * 64 + (lane & 15)) * 512 + ((lane >> 4) * 8);
  f4 acc[4] = {{0.f,0.f,0.f,0.f},{0.f,0.f,0.f,0.f},{0.f,0.f,0.f,0.f},{0.f,0.f,0.f,0.f}};
#pragma unroll
  for (int kk = 0; kk < 16; ++kk) {
    bf8 a = *(const bf8*)(ap + kk * 32);
#pragma unroll
    for (int jt = 0; jt < 4; ++jt) {
      bf8 b = *(const bf8*)(bp + jt * 16 * 512 + kk * 32);
      acc[jt] = __builtin_amdgcn_mfma_f32_16x16x32_bf16(a, b, acc[jt], 0, 0, 0);
    }
  }
#pragma unroll
  for (int jt = 0; jt < 4; ++jt) {
    int col = bn * 64 + jt * 16 + (lane & 15);
    float bv = bias[col];
#pragma unroll
    for (int i = 0; i < 4; ++i) {
      int row = r0 + (lane >> 4) * 4 + i;
      out[(size_t)row * 512 + col] = acc[jt][i] + bv;
    }
  }
}

extern "C" void kernel_launch(void* const* d_in, const int* in_sizes, int n_in,
                              void* d_out, int out_size, void* d_ws, size_t ws_size,
                              hipStream_t stream) {
  const float* x  = (const float*)d_in[0];
  const float* Wq = (const float*)d_in[1];
  const float* Wo = (const float*)d_in[2];
  const float* bo = (const float*)d_in[3];
  char* ws = (char*)d_ws;
  __bf16* xb  = (__bf16*)(ws + XB_OFF);
  __bf16* wqt = (__bf16*)(ws + WQT_OFF);
  __bf16* wot = (__bf16*)(ws + WOT_OFF);
  __bf16* Qh  = (__bf16*)(ws + Q_OFF);
  __bf16* Kh  = (__bf16*)(ws + K_OFF);
  __bf16* Vh  = (__bf16*)(ws + V_OFF);
  __bf16* AO  = (__bf16*)(ws + AO_OFF);
  _Float16* Sg = (_Float16*)(ws + SG_OFF);

  prep_kernel<<<(ROWS * DIM) / 256, 256, 0, stream>>>(x, Wq, Wo, xb, wqt, wot);
  qkv_gemm<<<(ROWS / 64) * (3 * INNER / 64), 256, 0, stream>>>(xb, wqt, Qh, Kh, Vh);
  for (int c = 0; c < 4; ++c) {             // 4-head chunks through the 32 MB S buffer
    qk_gemm<<<1024, 256, 0, stream>>>(Qh, Kh, Sg, c * 4);
    sparse_pv<<<1024, 512, 0, stream>>>(Sg, Vh, AO, c * 4);
  }
  out_gemm<<<(ROWS / 64) * (INNER / 64), 256, 0, stream>>>(AO, wot, bo, (float*)d_out);
}

// Round 14
// 225.508 us; speedup vs baseline: 1.4140x; 1.0281x over previous
//
#include <hip/hip_runtime.h>

typedef __bf16 bf8 __attribute__((ext_vector_type(8)));
typedef float f4 __attribute__((ext_vector_type(4)));
typedef _Float16 h8 __attribute__((ext_vector_type(8)));
typedef _Float16 h2 __attribute__((ext_vector_type(2)));

// Problem constants (fixed by reference)
constexpr int BSZ = 2, NSEQ = 2048, DIM = 512, NH = 8, DH = 64, INNER = 512;
constexpr int ROWS = BSZ * NSEQ;          // 4096

// Workspace layout (bytes)
constexpr size_t XB_OFF  = 0;                          // x cast bf16: 4 MB
constexpr size_t WQT_OFF = 4194304;                    // W_qkv^T bf16: 1.5 MB
constexpr size_t WOT_OFF = WQT_OFF + 1572864;          // W_out^T bf16: 0.5 MB
constexpr size_t Q_OFF   = WOT_OFF + 524288;           // Q/8 bf16 [16][2048][64]: 4 MB
constexpr size_t K_OFF   = Q_OFF + 4194304;            // K bf16: 4 MB
constexpr size_t V_OFF   = K_OFF + 4194304;            // V bf16: 4 MB
constexpr size_t AO_OFF  = V_OFF + 4194304;            // attn out bf16 [4096][512]: 4 MB
constexpr size_t SG_OFF  = AO_OFF + 4194304;           // S chunk f16 [4][2048][2048]: 32 MB
constexpr size_t BM_OFF  = SG_OFF + 33554432;          // bmax f32 [4][2048][16]: 512 KB
// total ~55 MB

// ---------------- prep: cast x to bf16; transpose+cast W_qkv, W_out ----------------
__global__ __launch_bounds__(256) void prep_kernel(
    const float* __restrict__ x, const float* __restrict__ Wq, const float* __restrict__ Wo,
    __bf16* __restrict__ xb, __bf16* __restrict__ wqt, __bf16* __restrict__ wot) {
  int idx = blockIdx.x * 256 + threadIdx.x;
  if (idx < ROWS * DIM) xb[idx] = (__bf16)x[idx];
  if (idx < 3 * INNER * DIM) {            // wqt[n][k] = Wq[k][n]
    int n = idx >> 9, k = idx & 511;
    wqt[idx] = (__bf16)Wq[k * (3 * INNER) + n];
  }
  if (idx < INNER * DIM) {                // wot[n][k] = Wo[k][n]
    int n = idx >> 9, k = idx & 511;
    wot[idx] = (__bf16)Wo[k * DIM + n];
  }
}

// ---------------- kernel 1: qkv = x @ W_qkv -> Q/8,K,V.  128x128 tile, BK=64, ----
// T14 reg-staged LDS pipeline: issue loads for step k+1 before computing step k.
__global__ __launch_bounds__(256) void qkv_gemm(
    const __bf16* __restrict__ xb, const __bf16* __restrict__ wqt,
    __bf16* __restrict__ Qh, __bf16* __restrict__ Kh, __bf16* __restrict__ Vh) {
  __shared__ __bf16 Asm[128 * 64];          // byte = r*128 + (chbyte ^ ((r&7)<<4))
  __shared__ __bf16 Bsm[128 * 64];
  int bid = blockIdx.x;
  int bn = bid % 12, bm = bid / 12;         // 12 col-tiles x 32 row-tiles of 128
  int t = threadIdx.x, lane = t & 63, wid = t >> 6;
  int wy = wid >> 1, wx = wid & 1;
  int l15 = lane & 15, lg = lane >> 4;
  // staging geometry: thread t covers rows j*32+(t>>3), 16B chunk (t&7)
  int sr = t >> 3, sc = t & 7;
  const __bf16* Ag = xb  + (size_t)(bm * 128 + sr) * 512 + sc * 8;
  const __bf16* Bg = wqt + (size_t)(bn * 128 + sr) * 512 + sc * 8;
  int swz = (sc * 16) ^ ((sr & 7) << 4);    // (j*32 preserves r&7)
  bf8 ra[4], rb[4];
#pragma unroll
  for (int j = 0; j < 4; ++j) {
    ra[j] = *(const bf8*)(Ag + (size_t)(j * 32) * 512);
    rb[j] = *(const bf8*)(Bg + (size_t)(j * 32) * 512);
  }
  f4 acc[4][4];
#pragma unroll
  for (int mt = 0; mt < 4; ++mt)
#pragma unroll
    for (int nt = 0; nt < 4; ++nt) acc[mt][nt] = (f4){0.f, 0.f, 0.f, 0.f};

  for (int ks = 0; ks < 8; ++ks) {
    __syncthreads();                        // all waves done reading previous tile
#pragma unroll
    for (int j = 0; j < 4; ++j) {
      *(bf8*)((char*)Asm + (size_t)(j * 32 + sr) * 128 + swz) = ra[j];
      *(bf8*)((char*)Bsm + (size_t)(j * 32 + sr) * 128 + swz) = rb[j];
    }
    if (ks < 7) {                           // issue next-tile loads; they fly during MFMA
      const __bf16* Ag2 = Ag + (ks + 1) * 64;
      const __bf16* Bg2 = Bg + (ks + 1) * 64;
#pragma unroll
      for (int j = 0; j < 4; ++j) {
        ra[j] = *(const bf8*)(Ag2 + (size_t)(j * 32) * 512);
        rb[j] = *(const bf8*)(Bg2 + (size_t)(j * 32) * 512);
      }
    }
    __syncthreads();                        // LDS tile ready (lgkm drained)
#pragma unroll
    for (int kk = 0; kk < 2; ++kk) {
      bf8 af[4], bg[4];
#pragma unroll
      for (int mt = 0; mt < 4; ++mt) {
        int r = wy * 64 + mt * 16 + l15;
        af[mt] = *(const bf8*)((const char*)Asm + (size_t)r * 128 +
                               ((kk * 64 + lg * 16) ^ ((r & 7) << 4)));
      }
#pragma unroll
      for (int nt = 0; nt < 4; ++nt) {
        int r = wx * 64 + nt * 16 + l15;
        bg[nt] = *(const bf8*)((const char*)Bsm + (size_t)r * 128 +
                               ((kk * 64 + lg * 16) ^ ((r & 7) << 4)));
      }
#pragma unroll
      for (int mt = 0; mt < 4; ++mt)
#pragma unroll
        for (int nt = 0; nt < 4; ++nt)
          acc[mt][nt] = __builtin_amdgcn_mfma_f32_16x16x32_bf16(af[mt], bg[nt], acc[mt][nt], 0, 0, 0);
    }
  }
  // epilogue: scatter into Q/8, K, V
#pragma unroll
  for (int mt = 0; mt < 4; ++mt)
#pragma unroll
    for (int nt = 0; nt < 4; ++nt) {
      int col = bn * 128 + wx * 64 + nt * 16 + l15;
      int which = col >> 9;                  // 0=q 1=k 2=v
      int inner = col & 511;
      int h = inner >> 6, d = inner & 63;
      __bf16* dst = which == 0 ? Qh : (which == 1 ? Kh : Vh);
      float scale = which == 0 ? 0.125f : 1.0f;
#pragma unroll
      for (int i = 0; i < 4; ++i) {
        int row = bm * 128 + wy * 64 + mt * 16 + lg * 4 + i;
        int b = row >> 11, n = row & 2047;
        dst[(((size_t)(b * 8 + h)) * 2048 + n) * 64 + d] = (__bf16)(acc[mt][nt][i] * scale);
      }
    }
}

// ---------------- kernel 2a: S = (Q/8) @ K^T + per-block row-max, 128x128 tiles ----
__global__ __launch_bounds__(256, 4) void qk_gemm(
    const __bf16* __restrict__ Qh, const __bf16* __restrict__ Kh,
    _Float16* __restrict__ Sg, float* __restrict__ bmax, int bh0) {
  __shared__ _Float16 ct[4][32][128];       // 32 KB, col ^ (((row>>2)&3)<<4)
  int bid = blockIdx.x;
  int hh = bid >> 8;                        // 0..3 head within chunk
  int rt = (bid >> 4) & 15;                 // q row-tile (128)
  int colt = bid & 15;                      // k col-tile (128)
  int lane = threadIdx.x & 63, wid = threadIdx.x >> 6;
  int bh = bh0 + hh;
  int l15 = lane & 15, lg = lane >> 4, koff = lg * 8;
  const __bf16* Qp = Qh + ((size_t)bh * 2048 + rt * 128 + wid * 32) * 64;
  const __bf16* Kp = Kh + ((size_t)bh * 2048 + colt * 128) * 64;

  bf8 aA0 = *(const bf8*)(Qp + l15 * 64 + koff);
  bf8 aA1 = *(const bf8*)(Qp + l15 * 64 + 32 + koff);
  bf8 aB0 = *(const bf8*)(Qp + (16 + l15) * 64 + koff);
  bf8 aB1 = *(const bf8*)(Qp + (16 + l15) * 64 + 32 + koff);
  f4 acc[2][8];
#pragma unroll
  for (int s = 0; s < 2; ++s)
#pragma unroll
    for (int j = 0; j < 8; ++j) acc[s][j] = (f4){0.f, 0.f, 0.f, 0.f};
#pragma unroll
  for (int ctj = 0; ctj < 8; ++ctj) {
    const __bf16* kb = Kp + (size_t)(ctj * 16 + l15) * 64 + koff;
    bf8 b0 = *(const bf8*)(kb);
    bf8 b1 = *(const bf8*)(kb + 32);
    acc[0][ctj] = __builtin_amdgcn_mfma_f32_16x16x32_bf16(aA0, b0, acc[0][ctj], 0, 0, 0);
    acc[0][ctj] = __builtin_amdgcn_mfma_f32_16x16x32_bf16(aA1, b1, acc[0][ctj], 0, 0, 0);
    acc[1][ctj] = __builtin_amdgcn_mfma_f32_16x16x32_bf16(aB0, b0, acc[1][ctj], 0, 0, 0);
    acc[1][ctj] = __builtin_amdgcn_mfma_f32_16x16x32_bf16(aB1, b1, acc[1][ctj], 0, 0, 0);
  }
  // per-block row-max (for sparse_pv's filter): reduce over ctj (regs) then l15 (shfl)
#pragma unroll
  for (int s = 0; s < 2; ++s)
#pragma unroll
    for (int i = 0; i < 4; ++i) {
      float rm = acc[s][0][i];
#pragma unroll
      for (int ctj = 1; ctj < 8; ++ctj) rm = fmaxf(rm, acc[s][ctj][i]);
#pragma unroll
      for (int o = 1; o < 16; o <<= 1) rm = fmaxf(rm, __shfl_xor(rm, o));
      if (l15 == 0) {
        int row = rt * 128 + wid * 32 + s * 16 + lg * 4 + i;
        bmax[((size_t)hh * 2048 + row) * 16 + colt] = rm;
      }
    }
  // repack to wave-private LDS (XOR-swizzled) -> coalesced full-row stores
#pragma unroll
  for (int s = 0; s < 2; ++s)
#pragma unroll
    for (int ctj = 0; ctj < 8; ++ctj)
#pragma unroll
      for (int i = 0; i < 4; ++i) {
        int row = s * 16 + lg * 4 + i;
        int col = ctj * 16 + l15;
        ct[wid][row][col ^ (((row >> 2) & 3) << 4)] = (_Float16)acc[s][ctj][i];
      }
  int r4 = lane >> 4, ch = lane & 15;
  size_t srow0 = (size_t)hh * 2048 + rt * 128 + wid * 32;
#pragma unroll
  for (int it = 0; it < 8; ++it) {
    int r = it * 4 + r4;
    h8 v = *(const h8*)&ct[wid][r][(ch * 8) ^ (((r >> 2) & 3) << 4)];
    *(h8*)&Sg[(srow0 + r) * 2048 + colt * 128 + ch * 8] = v;
  }
}

// ---------------- kernel 2b: bmax-filtered sparsemax + sparse PV, one wave/row ----
__global__ __launch_bounds__(512, 8) void sparse_pv(
    const _Float16* __restrict__ Sg, const float* __restrict__ bmax,
    const __bf16* __restrict__ Vh, __bf16* __restrict__ AO, int bh0) {
  __shared__ float candv[8][64];            // 2 KB
  __shared__ int   candj[8][64];            // 2 KB
  int lane = threadIdx.x & 63, wid = threadIdx.x >> 6;   // 8 waves
  int rowid = blockIdx.x * 8 + wid;
  int hh = rowid >> 11, n = rowid & 2047;
  int bh = bh0 + hh;
  const _Float16* Srow = Sg + ((size_t)hh * 2048 + n) * 2048;
  const float* bmr = bmax + ((size_t)hh * 2048 + n) * 16;
  const __bf16* Vp = Vh + (size_t)bh * 2048 * 64;

  float bmv[16];
  *(f4*)&bmv[0]  = *(const f4*)&bmr[0];
  *(f4*)&bmv[4]  = *(const f4*)&bmr[4];
  *(f4*)&bmv[8]  = *(const f4*)&bmr[8];
  *(f4*)&bmv[12] = *(const f4*)&bmr[12];
  float gmax = bmv[0];
#pragma unroll
  for (int ct = 1; ct < 16; ++ct) gmax = fmaxf(gmax, bmv[ct]);
  // tau* >= max-1; 0.02 slack covers f16 rounding of stored S vs f32 bmax.
  float tau0 = gmax - 1.02f;

  candv[wid][lane] = -1e30f;                // prefill so unwritten slots are inert
  candj[wid][lane] = 0;
  int base = 0; bool ovf = false;
#pragma unroll
  for (int ct = 0; ct < 16; ++ct) {
    if (bmv[ct] > tau0) {                   // row-uniform -> wave-uniform
      h2 zz = *(const h2*)&Srow[ct * 128 + lane * 2];
      float z0 = (float)zz[0], z1 = (float)zz[1];
      int m = (z0 > tau0 ? 1 : 0) | (z1 > tau0 ? 2 : 0);
      int pc = __popc((unsigned)m);
      int off = pc;
#pragma unroll
      for (int d = 1; d < 64; d <<= 1) {
        int tt = __shfl_up(off, d);
        if (lane >= d) off += tt;
      }
      int tot = __shfl(off, 63);
      off -= pc;
      if (base + tot <= 64) {
        int slot = base + off;
        if (m & 1) { candv[wid][slot] = z0; candj[wid][slot] = ct * 128 + lane * 2; ++slot; }
        if (m & 2) { candv[wid][slot] = z1; candj[wid][slot] = ct * 128 + lane * 2 + 1; }
      } else ovf = true;
      base += tot;
    }
  }
  int total = base;
  float tau = tau0, acc_o = 0.f;
  if (!ovf) {
    if (total <= 16) {
      // register path: 4 broadcast b128 loads, pure-VALU Michelot, branchless gather
      f4 cv0 = *(const f4*)&candv[wid][0];
      f4 cv1 = *(const f4*)&candv[wid][4];
      f4 cv2 = *(const f4*)&candv[wid][8];
      f4 cv3 = *(const f4*)&candv[wid][12];
      float cprev = -1.0f;
      for (int it = 0; it < 20; ++it) {
        float s = 0.f, c = 0.f;
#pragma unroll
        for (int i = 0; i < 4; ++i) {
          if (cv0[i] > tau) { s += cv0[i]; c += 1.f; }
          if (cv1[i] > tau) { s += cv1[i]; c += 1.f; }
          if (cv2[i] > tau) { s += cv2[i]; c += 1.f; }
          if (cv3[i] > tau) { s += cv3[i]; c += 1.f; }
        }
        if (c == cprev) break;
        tau = (s - 1.0f) / c; cprev = c;
      }
      const __bf16* vb = Vp + lane;
#pragma unroll
      for (int jc = 0; jc < 4; ++jc) {
        f4 cj = jc == 0 ? cv0 : (jc == 1 ? cv1 : (jc == 2 ? cv2 : cv3));
        int j0 = candj[wid][jc * 4 + 0];
        int j1 = candj[wid][jc * 4 + 1];
        int j2 = candj[wid][jc * 4 + 2];
        int j3 = candj[wid][jc * 4 + 3];
        acc_o += fmaxf(cj[0] - tau, 0.f) * (float)vb[(size_t)j0 * 64];
        acc_o += fmaxf(cj[1] - tau, 0.f) * (float)vb[(size_t)j1 * 64];
        acc_o += fmaxf(cj[2] - tau, 0.f) * (float)vb[(size_t)j2 * 64];
        acc_o += fmaxf(cj[3] - tau, 0.f) * (float)vb[(size_t)j3 * 64];
      }
    } else {
      // mid path: Michelot on 1 candidate per lane (butterfly reduce)
      float v = candv[wid][lane];
      bool valid = lane < total;
      float cprev = -1.0f;
      for (int it = 0; it < 24; ++it) {
        bool in = valid && (v > tau);
        float s = in ? v : 0.f, c = in ? 1.f : 0.f;
#pragma unroll
        for (int o = 32; o; o >>= 1) { s += __shfl_xor(s, o); c += __shfl_xor(c, o); }
        if (c == cprev) break;
        tau = (s - 1.0f) / c; cprev = c;
      }
      for (int j = 0; j < total; ++j) {
        float p = candv[wid][j] - tau;
        if (p > 0.f) {
          int idx = candj[wid][j];
          acc_o += p * (float)Vp[(size_t)idx * 64 + lane];
        }
      }
    }
  } else {
    // fallback (rare): read full row, full-register Michelot from tau0 + ballot gather
    h8 zc[4];
#pragma unroll
    for (int r = 0; r < 4; ++r)
      zc[r] = *(const h8*)&Srow[r * 512 + lane * 8];
    float cprev = -1.0f;
    for (int it = 0; it < 48; ++it) {
      float s = 0.f, c = 0.f;
#pragma unroll
      for (int r = 0; r < 4; ++r)
#pragma unroll
        for (int i = 0; i < 8; ++i) {
          float zz = (float)zc[r][i];
          if (zz > tau) { s += zz; c += 1.f; }
        }
#pragma unroll
      for (int o = 32; o; o >>= 1) { s += __shfl_xor(s, o); c += __shfl_xor(c, o); }
      if (c == cprev) break;
      tau = (s - 1.0f) / c; cprev = c;
    }
#pragma unroll
    for (int r = 0; r < 4; ++r)
#pragma unroll
      for (int i = 0; i < 8; ++i) {
        float p = (float)zc[r][i] - tau;
        unsigned long long m = __ballot(p > 0.f);
        while (m) {
          int src = __ffsll((long long)m) - 1;
          m &= m - 1;
          float pj = __shfl(p, src);
          int j = r * 512 + src * 8 + i;
          acc_o += pj * (float)Vp[(size_t)j * 64 + lane];
        }
      }
  }
  int rowg = (bh >> 3) * 2048 + n;          // [B][N] row
  AO[(size_t)rowg * 512 + (bh & 7) * 64 + lane] = (__bf16)acc_o;
}

// ---------------- kernel 3: out = AO @ W_out + b_out (f32 result) ----------------
__global__ __launch_bounds__(256) void out_gemm(
    const __bf16* __restrict__ A, const __bf16* __restrict__ wot,
    const float* __restrict__ bias, float* __restrict__ out) {
  int bid = blockIdx.x;
  int bn = bid & 7, bm = bid >> 3;
  int lane = threadIdx.x & 63, wid = threadIdx.x >> 6;
  int r0 = bm * 64 + wid * 16;
  const __bf16* ap = A   + (size_t)(r0 + (lane & 15)) * 512 + ((lane >> 4) * 8);
  const __bf16* bp = wot + (size_t)(bn * 64 + (lane & 15)) * 512 + ((lane >> 4) * 8);
  f4 acc[4] = {{0.f,0.f,0.f,0.f},{0.f,0.f,0.f,0.f},{0.f,0.f,0.f,0.f},{0.f,0.f,0.f,0.f}};
#pragma unroll
  for (int kk = 0; kk < 16; ++kk) {
    bf8 a = *(const bf8*)(ap + kk * 32);
#pragma unroll
    for (int jt = 0; jt < 4; ++jt) {
      bf8 b = *(const bf8*)(bp + jt * 16 * 512 + kk * 32);
      acc[jt] = __builtin_amdgcn_mfma_f32_16x16x32_bf16(a, b, acc[jt], 0, 0, 0);
    }
  }
#pragma unroll
  for (int jt = 0; jt < 4; ++jt) {
    int col = bn * 64 + jt * 16 + (lane & 15);
    float bv = bias[col];
#pragma unroll
    for (int i = 0; i < 4; ++i) {
      int row = r0 + (lane >> 4) * 4 + i;
      out[(size_t)row * 512 + col] = acc[jt][i] + bv;
    }
  }
}

extern "C" void kernel_launch(void* const* d_in, const int* in_sizes, int n_in,
                              void* d_out, int out_size, void* d_ws, size_t ws_size,
                              hipStream_t stream) {
  const float* x  = (const float*)d_in[0];
  const float* Wq = (const float*)d_in[1];
  const float* Wo = (const float*)d_in[2];
  const float* bo = (const float*)d_in[3];
  char* ws = (char*)d_ws;
  __bf16* xb  = (__bf16*)(ws + XB_OFF);
  __bf16* wqt = (__bf16*)(ws + WQT_OFF);
  __bf16* wot = (__bf16*)(ws + WOT_OFF);
  __bf16* Qh  = (__bf16*)(ws + Q_OFF);
  __bf16* Kh  = (__bf16*)(ws + K_OFF);
  __bf16* Vh  = (__bf16*)(ws + V_OFF);
  __bf16* AO  = (__bf16*)(ws + AO_OFF);
  _Float16* Sg = (_Float16*)(ws + SG_OFF);
  float* bm = (float*)(ws + BM_OFF);

  prep_kernel<<<(ROWS * DIM) / 256, 256, 0, stream>>>(x, Wq, Wo, xb, wqt, wot);
  qkv_gemm<<<32 * 12, 256, 0, stream>>>(xb, wqt, Qh, Kh, Vh);
  for (int c = 0; c < 4; ++c) {             // 4-head chunks through the 32 MB S buffer
    qk_gemm<<<1024, 256, 0, stream>>>(Qh, Kh, Sg, bm, c * 4);
    sparse_pv<<<1024, 512, 0, stream>>>(Sg, bm, Vh, AO, c * 4);
  }
  out_gemm<<<(ROWS / 64) * (INNER / 64), 256, 0, stream>>>(AO, wot, bo, (float*)d_out);
}

// Round 15
// 202.407 us; speedup vs baseline: 1.5754x; 1.1141x over previous
//
#include <hip/hip_runtime.h>

typedef __bf16 bf8 __attribute__((ext_vector_type(8)));
typedef float f4 __attribute__((ext_vector_type(4)));
typedef _Float16 h8 __attribute__((ext_vector_type(8)));
typedef _Float16 h2 __attribute__((ext_vector_type(2)));

// Problem constants (fixed by reference)
constexpr int BSZ = 2, NSEQ = 2048, DIM = 512, NH = 8, DH = 64, INNER = 512;
constexpr int ROWS = BSZ * NSEQ;          // 4096

// Workspace layout (bytes)
constexpr size_t XB_OFF  = 0;                          // x cast bf16: 4 MB
constexpr size_t WQT_OFF = 4194304;                    // W_qkv^T bf16: 1.5 MB
constexpr size_t WOT_OFF = WQT_OFF + 1572864;          // W_out^T bf16: 0.5 MB
constexpr size_t Q_OFF   = WOT_OFF + 524288;           // Q/8 bf16 [16][2048][64]: 4 MB
constexpr size_t K_OFF   = Q_OFF + 4194304;            // K bf16: 4 MB
constexpr size_t V_OFF   = K_OFF + 4194304;            // V bf16: 4 MB
constexpr size_t AO_OFF  = V_OFF + 4194304;            // attn out bf16 [4096][512]: 4 MB
constexpr size_t SG_OFF  = AO_OFF + 4194304;           // S chunk f16 [4][2048][2048]: 32 MB
constexpr size_t BM_OFF  = SG_OFF + 33554432;          // bmax f32 [4][2048][16]: 512 KB
// total ~55 MB

// ---------------- prep: cast x to bf16; transpose+cast W_qkv, W_out ----------------
__global__ __launch_bounds__(256) void prep_kernel(
    const float* __restrict__ x, const float* __restrict__ Wq, const float* __restrict__ Wo,
    __bf16* __restrict__ xb, __bf16* __restrict__ wqt, __bf16* __restrict__ wot) {
  int idx = blockIdx.x * 256 + threadIdx.x;
  if (idx < ROWS * DIM) xb[idx] = (__bf16)x[idx];
  if (idx < 3 * INNER * DIM) {            // wqt[n][k] = Wq[k][n]
    int n = idx >> 9, k = idx & 511;
    wqt[idx] = (__bf16)Wq[k * (3 * INNER) + n];
  }
  if (idx < INNER * DIM) {                // wot[n][k] = Wo[k][n]
    int n = idx >> 9, k = idx & 511;
    wot[idx] = (__bf16)Wo[k * DIM + n];
  }
}

// ---------------- kernel 1: qkv = x @ W_qkv -> Q/8,K,V.  128x128 tile, BK=64, ----
// T14 reg-staged LDS pipeline: issue loads for step k+1 before computing step k.
__global__ __launch_bounds__(256) void qkv_gemm(
    const __bf16* __restrict__ xb, const __bf16* __restrict__ wqt,
    __bf16* __restrict__ Qh, __bf16* __restrict__ Kh, __bf16* __restrict__ Vh) {
  __shared__ __bf16 Asm[128 * 64];          // byte = r*128 + (chbyte ^ ((r&7)<<4))
  __shared__ __bf16 Bsm[128 * 64];
  int bid = blockIdx.x;
  int bn = bid % 12, bm = bid / 12;         // 12 col-tiles x 32 row-tiles of 128
  int t = threadIdx.x, lane = t & 63, wid = t >> 6;
  int wy = wid >> 1, wx = wid & 1;
  int l15 = lane & 15, lg = lane >> 4;
  // staging geometry: thread t covers rows j*32+(t>>3), 16B chunk (t&7)
  int sr = t >> 3, sc = t & 7;
  const __bf16* Ag = xb  + (size_t)(bm * 128 + sr) * 512 + sc * 8;
  const __bf16* Bg = wqt + (size_t)(bn * 128 + sr) * 512 + sc * 8;
  int swz = (sc * 16) ^ ((sr & 7) << 4);    // (j*32 preserves r&7)
  bf8 ra[4], rb[4];
#pragma unroll
  for (int j = 0; j < 4; ++j) {
    ra[j] = *(const bf8*)(Ag + (size_t)(j * 32) * 512);
    rb[j] = *(const bf8*)(Bg + (size_t)(j * 32) * 512);
  }
  f4 acc[4][4];
#pragma unroll
  for (int mt = 0; mt < 4; ++mt)
#pragma unroll
    for (int nt = 0; nt < 4; ++nt) acc[mt][nt] = (f4){0.f, 0.f, 0.f, 0.f};

  for (int ks = 0; ks < 8; ++ks) {
    __syncthreads();                        // all waves done reading previous tile
#pragma unroll
    for (int j = 0; j < 4; ++j) {
      *(bf8*)((char*)Asm + (size_t)(j * 32 + sr) * 128 + swz) = ra[j];
      *(bf8*)((char*)Bsm + (size_t)(j * 32 + sr) * 128 + swz) = rb[j];
    }
    if (ks < 7) {                           // issue next-tile loads; they fly during MFMA
      const __bf16* Ag2 = Ag + (ks + 1) * 64;
      const __bf16* Bg2 = Bg + (ks + 1) * 64;
#pragma unroll
      for (int j = 0; j < 4; ++j) {
        ra[j] = *(const bf8*)(Ag2 + (size_t)(j * 32) * 512);
        rb[j] = *(const bf8*)(Bg2 + (size_t)(j * 32) * 512);
      }
    }
    __syncthreads();                        // LDS tile ready (lgkm drained)
#pragma unroll
    for (int kk = 0; kk < 2; ++kk) {
      bf8 af[4], bg[4];
#pragma unroll
      for (int mt = 0; mt < 4; ++mt) {
        int r = wy * 64 + mt * 16 + l15;
        af[mt] = *(const bf8*)((const char*)Asm + (size_t)r * 128 +
                               ((kk * 64 + lg * 16) ^ ((r & 7) << 4)));
      }
#pragma unroll
      for (int nt = 0; nt < 4; ++nt) {
        int r = wx * 64 + nt * 16 + l15;
        bg[nt] = *(const bf8*)((const char*)Bsm + (size_t)r * 128 +
                               ((kk * 64 + lg * 16) ^ ((r & 7) << 4)));
      }
#pragma unroll
      for (int mt = 0; mt < 4; ++mt)
#pragma unroll
        for (int nt = 0; nt < 4; ++nt)
          acc[mt][nt] = __builtin_amdgcn_mfma_f32_16x16x32_bf16(af[mt], bg[nt], acc[mt][nt], 0, 0, 0);
    }
  }
  // epilogue: scatter into Q/8, K, V
#pragma unroll
  for (int mt = 0; mt < 4; ++mt)
#pragma unroll
    for (int nt = 0; nt < 4; ++nt) {
      int col = bn * 128 + wx * 64 + nt * 16 + l15;
      int which = col >> 9;                  // 0=q 1=k 2=v
      int inner = col & 511;
      int h = inner >> 6, d = inner & 63;
      __bf16* dst = which == 0 ? Qh : (which == 1 ? Kh : Vh);
      float scale = which == 0 ? 0.125f : 1.0f;
#pragma unroll
      for (int i = 0; i < 4; ++i) {
        int row = bm * 128 + wy * 64 + mt * 16 + lg * 4 + i;
        int b = row >> 11, n = row & 2047;
        dst[(((size_t)(b * 8 + h)) * 2048 + n) * 64 + d] = (__bf16)(acc[mt][nt][i] * scale);
      }
    }
}

// ---------------- kernel 2a: S = (Q/8) @ K^T + per-block row-max, 128x128 tiles ----
// K-tile LDS-staged once per block (shared by 4 waves); LDS reused for store repack.
__global__ __launch_bounds__(256) void qk_gemm(
    const __bf16* __restrict__ Qh, const __bf16* __restrict__ Kh,
    _Float16* __restrict__ Sg, float* __restrict__ bmax, int bh0) {
  __shared__ char lds[32768];               // [0,16K): K-tile; later: ct[4][32][128]
  int bid = blockIdx.x;
  int hh = bid >> 8;                        // 0..3 head within chunk
  int rt = (bid >> 4) & 15;                 // q row-tile (128)
  int colt = bid & 15;                      // k col-tile (128)
  int t = threadIdx.x, lane = t & 63, wid = t >> 6;
  int bh = bh0 + hh;
  int l15 = lane & 15, lg = lane >> 4;

  // stage K-tile [128 rows][64 dims] cooperatively, swizzled (rule #21 both-sides)
  {
    int sr = t >> 3, sc = t & 7;            // 32 rows/pass, full 128B rows coalesced
    const __bf16* Kg = Kh + ((size_t)bh * 2048 + colt * 128 + sr) * 64 + sc * 8;
    bf8 k0 = *(const bf8*)(Kg);
    bf8 k1 = *(const bf8*)(Kg + 32 * 64);
    bf8 k2 = *(const bf8*)(Kg + 64 * 64);
    bf8 k3 = *(const bf8*)(Kg + 96 * 64);
    int swz = (sc * 16) ^ ((sr & 7) << 4);  // +32j preserves r&7
    *(bf8*)(lds + (size_t)sr * 128 + swz) = k0;
    *(bf8*)(lds + (size_t)(sr + 32) * 128 + swz) = k1;
    *(bf8*)(lds + (size_t)(sr + 64) * 128 + swz) = k2;
    *(bf8*)(lds + (size_t)(sr + 96) * 128 + swz) = k3;
  }
  const __bf16* Qp = Qh + ((size_t)bh * 2048 + rt * 128 + wid * 32) * 64;
  bf8 aA0 = *(const bf8*)(Qp + l15 * 64 + lg * 8);
  bf8 aA1 = *(const bf8*)(Qp + l15 * 64 + 32 + lg * 8);
  bf8 aB0 = *(const bf8*)(Qp + (16 + l15) * 64 + lg * 8);
  bf8 aB1 = *(const bf8*)(Qp + (16 + l15) * 64 + 32 + lg * 8);
  __syncthreads();                          // K-tile ready

  f4 acc[2][8];
#pragma unroll
  for (int s = 0; s < 2; ++s)
#pragma unroll
    for (int j = 0; j < 8; ++j) acc[s][j] = (f4){0.f, 0.f, 0.f, 0.f};
#pragma unroll
  for (int ctj = 0; ctj < 8; ++ctj) {
    int r = ctj * 16 + l15;
    const char* kb = lds + (size_t)r * 128;
    int sw = (r & 7) << 4;
    bf8 b0 = *(const bf8*)(kb + ((lg * 16) ^ sw));        // dims lg*8..+8
    bf8 b1 = *(const bf8*)(kb + ((64 + lg * 16) ^ sw));   // dims 32+lg*8..+8
    acc[0][ctj] = __builtin_amdgcn_mfma_f32_16x16x32_bf16(aA0, b0, acc[0][ctj], 0, 0, 0);
    acc[0][ctj] = __builtin_amdgcn_mfma_f32_16x16x32_bf16(aA1, b1, acc[0][ctj], 0, 0, 0);
    acc[1][ctj] = __builtin_amdgcn_mfma_f32_16x16x32_bf16(aB0, b0, acc[1][ctj], 0, 0, 0);
    acc[1][ctj] = __builtin_amdgcn_mfma_f32_16x16x32_bf16(aB1, b1, acc[1][ctj], 0, 0, 0);
  }
  // per-block row-max (for sparse_pv's filter)
#pragma unroll
  for (int s = 0; s < 2; ++s)
#pragma unroll
    for (int i = 0; i < 4; ++i) {
      float rm = acc[s][0][i];
#pragma unroll
      for (int ctj = 1; ctj < 8; ++ctj) rm = fmaxf(rm, acc[s][ctj][i]);
#pragma unroll
      for (int o = 1; o < 16; o <<= 1) rm = fmaxf(rm, __shfl_xor(rm, o));
      if (l15 == 0) {
        int row = rt * 128 + wid * 32 + s * 16 + lg * 4 + i;
        bmax[((size_t)hh * 2048 + row) * 16 + colt] = rm;
      }
    }
  __syncthreads();                          // all waves done reading K-tile; reuse LDS
  _Float16 (*ct)[32][128] = (_Float16(*)[32][128])lds;
#pragma unroll
  for (int s = 0; s < 2; ++s)
#pragma unroll
    for (int ctj = 0; ctj < 8; ++ctj)
#pragma unroll
      for (int i = 0; i < 4; ++i) {
        int row = s * 16 + lg * 4 + i;
        int col = ctj * 16 + l15;
        ct[wid][row][col ^ (((row >> 2) & 3) << 4)] = (_Float16)acc[s][ctj][i];
      }
  int r4 = lane >> 4, ch = lane & 15;       // wave-private region: no barrier needed
  size_t srow0 = (size_t)hh * 2048 + rt * 128 + wid * 32;
#pragma unroll
  for (int it = 0; it < 8; ++it) {
    int r = it * 4 + r4;
    h8 v = *(const h8*)&ct[wid][r][(ch * 8) ^ (((r >> 2) & 3) << 4)];
    *(h8*)&Sg[(srow0 + r) * 2048 + colt * 128 + ch * 8] = v;
  }
}

// ---------------- kernel 2b: bmax-filtered sparsemax + sparse PV, one wave/row ----
__global__ __launch_bounds__(512, 8) void sparse_pv(
    const _Float16* __restrict__ Sg, const float* __restrict__ bmax,
    const __bf16* __restrict__ Vh, __bf16* __restrict__ AO, int bh0) {
  __shared__ float candv[8][64];            // 2 KB
  __shared__ int   candj[8][64];            // 2 KB
  int lane = threadIdx.x & 63, wid = threadIdx.x >> 6;   // 8 waves
  int rowid = blockIdx.x * 8 + wid;
  int hh = rowid >> 11, n = rowid & 2047;
  int bh = bh0 + hh;
  const _Float16* Srow = Sg + ((size_t)hh * 2048 + n) * 2048;
  const float* bmr = bmax + ((size_t)hh * 2048 + n) * 16;
  const __bf16* Vp = Vh + (size_t)bh * 2048 * 64;

  float bmv[16];
  *(f4*)&bmv[0]  = *(const f4*)&bmr[0];
  *(f4*)&bmv[4]  = *(const f4*)&bmr[4];
  *(f4*)&bmv[8]  = *(const f4*)&bmr[8];
  *(f4*)&bmv[12] = *(const f4*)&bmr[12];
  float gmax = bmv[0];
#pragma unroll
  for (int ct = 1; ct < 16; ++ct) gmax = fmaxf(gmax, bmv[ct]);
  // tau* >= max-1; 0.02 slack covers f16 rounding of stored S vs f32 bmax.
  float tau0 = gmax - 1.02f;

  candv[wid][lane] = -1e30f;                // prefill so unwritten slots are inert
  candj[wid][lane] = 0;
  int base = 0; bool ovf = false;
#pragma unroll
  for (int ct = 0; ct < 16; ++ct) {
    if (bmv[ct] > tau0) {                   // row-uniform -> wave-uniform
      h2 zz = *(const h2*)&Srow[ct * 128 + lane * 2];
      float z0 = (float)zz[0], z1 = (float)zz[1];
      int m = (z0 > tau0 ? 1 : 0) | (z1 > tau0 ? 2 : 0);
      int pc = __popc((unsigned)m);
      int off = pc;
#pragma unroll
      for (int d = 1; d < 64; d <<= 1) {
        int tt = __shfl_up(off, d);
        if (lane >= d) off += tt;
      }
      int tot = __shfl(off, 63);
      off -= pc;
      if (base + tot <= 64) {
        int slot = base + off;
        if (m & 1) { candv[wid][slot] = z0; candj[wid][slot] = ct * 128 + lane * 2; ++slot; }
        if (m & 2) { candv[wid][slot] = z1; candj[wid][slot] = ct * 128 + lane * 2 + 1; }
      } else ovf = true;
      base += tot;
    }
  }
  int total = base;
  float tau = tau0, acc_o = 0.f;
  if (!ovf) {
    if (total <= 16) {
      // register path: 4 broadcast b128 loads, pure-VALU Michelot, branchless gather
      f4 cv0 = *(const f4*)&candv[wid][0];
      f4 cv1 = *(const f4*)&candv[wid][4];
      f4 cv2 = *(const f4*)&candv[wid][8];
      f4 cv3 = *(const f4*)&candv[wid][12];
      float cprev = -1.0f;
      for (int it = 0; it < 20; ++it) {
        float s = 0.f, c = 0.f;
#pragma unroll
        for (int i = 0; i < 4; ++i) {
          if (cv0[i] > tau) { s += cv0[i]; c += 1.f; }
          if (cv1[i] > tau) { s += cv1[i]; c += 1.f; }
          if (cv2[i] > tau) { s += cv2[i]; c += 1.f; }
          if (cv3[i] > tau) { s += cv3[i]; c += 1.f; }
        }
        if (c == cprev) break;
        tau = (s - 1.0f) / c; cprev = c;
      }
      const __bf16* vb = Vp + lane;
#pragma unroll
      for (int jc = 0; jc < 4; ++jc) {
        f4 cj = jc == 0 ? cv0 : (jc == 1 ? cv1 : (jc == 2 ? cv2 : cv3));
        int j0 = candj[wid][jc * 4 + 0];
        int j1 = candj[wid][jc * 4 + 1];
        int j2 = candj[wid][jc * 4 + 2];
        int j3 = candj[wid][jc * 4 + 3];
        acc_o += fmaxf(cj[0] - tau, 0.f) * (float)vb[(size_t)j0 * 64];
        acc_o += fmaxf(cj[1] - tau, 0.f) * (float)vb[(size_t)j1 * 64];
        acc_o += fmaxf(cj[2] - tau, 0.f) * (float)vb[(size_t)j2 * 64];
        acc_o += fmaxf(cj[3] - tau, 0.f) * (float)vb[(size_t)j3 * 64];
      }
    } else {
      // mid path: Michelot on 1 candidate per lane (butterfly reduce)
      float v = candv[wid][lane];
      bool valid = lane < total;
      float cprev = -1.0f;
      for (int it = 0; it < 24; ++it) {
        bool in = valid && (v > tau);
        float s = in ? v : 0.f, c = in ? 1.f : 0.f;
#pragma unroll
        for (int o = 32; o; o >>= 1) { s += __shfl_xor(s, o); c += __shfl_xor(c, o); }
        if (c == cprev) break;
        tau = (s - 1.0f) / c; cprev = c;
      }
      for (int j = 0; j < total; ++j) {
        float p = candv[wid][j] - tau;
        if (p > 0.f) {
          int idx = candj[wid][j];
          acc_o += p * (float)Vp[(size_t)idx * 64 + lane];
        }
      }
    }
  } else {
    // fallback (rare): read full row, full-register Michelot from tau0 + ballot gather
    h8 zc[4];
#pragma unroll
    for (int r = 0; r < 4; ++r)
      zc[r] = *(const h8*)&Srow[r * 512 + lane * 8];
    float cprev = -1.0f;
    for (int it = 0; it < 48; ++it) {
      float s = 0.f, c = 0.f;
#pragma unroll
      for (int r = 0; r < 4; ++r)
#pragma unroll
        for (int i = 0; i < 8; ++i) {
          float zz = (float)zc[r][i];
          if (zz > tau) { s += zz; c += 1.f; }
        }
#pragma unroll
      for (int o = 32; o; o >>= 1) { s += __shfl_xor(s, o); c += __shfl_xor(c, o); }
      if (c == cprev) break;
      tau = (s - 1.0f) / c; cprev = c;
    }
#pragma unroll
    for (int r = 0; r < 4; ++r)
#pragma unroll
      for (int i = 0; i < 8; ++i) {
        float p = (float)zc[r][i] - tau;
        unsigned long long m = __ballot(p > 0.f);
        while (m) {
          int src = __ffsll((long long)m) - 1;
          m &= m - 1;
          float pj = __shfl(p, src);
          int j = r * 512 + src * 8 + i;
          acc_o += pj * (float)Vp[(size_t)j * 64 + lane];
        }
      }
  }
  int rowg = (bh >> 3) * 2048 + n;          // [B][N] row
  AO[(size_t)rowg * 512 + (bh & 7) * 64 + lane] = (__bf16)acc_o;
}

// ---------------- kernel 3: out = AO @ W_out + b_out (f32 result) ----------------
__global__ __launch_bounds__(256) void out_gemm(
    const __bf16* __restrict__ A, const __bf16* __restrict__ wot,
    const float* __restrict__ bias, float* __restrict__ out) {
  int bid = blockIdx.x;
  int bn = bid & 7, bm = bid >> 3;
  int lane = threadIdx.x & 63, wid = threadIdx.x >> 6;
  int r0 = bm * 64 + wid * 16;
  const __bf16* ap = A   + (size_t)(r0 + (lane & 15)) * 512 + ((lane >> 4) * 8);
  const __bf16* bp = wot + (size_t)(bn * 64 + (lane & 15)) * 512 + ((lane >> 4) * 8);
  f4 acc[4] = {{0.f,0.f,0.f,0.f},{0.f,0.f,0.f,0.f},{0.f,0.f,0.f,0.f},{0.f,0.f,0.f,0.f}};
#pragma unroll
  for (int kk = 0; kk < 16; ++kk) {
    bf8 a = *(const bf8*)(ap + kk * 32);
#pragma unroll
    for (int jt = 0; jt < 4; ++jt) {
      bf8 b = *(const bf8*)(bp + jt * 16 * 512 + kk * 32);
      acc[jt] = __builtin_amdgcn_mfma_f32_16x16x32_bf16(a, b, acc[jt], 0, 0, 0);
    }
  }
#pragma unroll
  for (int jt = 0; jt < 4; ++jt) {
    int col = bn * 64 + jt * 16 + (lane & 15);
    float bv = bias[col];
#pragma unroll
    for (int i = 0; i < 4; ++i) {
      int row = r0 + (lane >> 4) * 4 + i;
      out[(size_t)row * 512 + col] = acc[jt][i] + bv;
    }
  }
}

extern "C" void kernel_launch(void* const* d_in, const int* in_sizes, int n_in,
                              void* d_out, int out_size, void* d_ws, size_t ws_size,
                              hipStream_t stream) {
  const float* x  = (const float*)d_in[0];
  const float* Wq = (const float*)d_in[1];
  const float* Wo = (const float*)d_in[2];
  const float* bo = (const float*)d_in[3];
  char* ws = (char*)d_ws;
  __bf16* xb  = (__bf16*)(ws + XB_OFF);
  __bf16* wqt = (__bf16*)(ws + WQT_OFF);
  __bf16* wot = (__bf16*)(ws + WOT_OFF);
  __bf16* Qh  = (__bf16*)(ws + Q_OFF);
  __bf16* Kh  = (__bf16*)(ws + K_OFF);
  __bf16* Vh  = (__bf16*)(ws + V_OFF);
  __bf16* AO  = (__bf16*)(ws + AO_OFF);
  _Float16* Sg = (_Float16*)(ws + SG_OFF);
  float* bm = (float*)(ws + BM_OFF);

  prep_kernel<<<(ROWS * DIM) / 256, 256, 0, stream>>>(x, Wq, Wo, xb, wqt, wot);
  qkv_gemm<<<32 * 12, 256, 0, stream>>>(xb, wqt, Qh, Kh, Vh);
  for (int c = 0; c < 4; ++c) {             // 4-head chunks through the 32 MB S buffer
    qk_gemm<<<1024, 256, 0, stream>>>(Qh, Kh, Sg, bm, c * 4);
    sparse_pv<<<1024, 512, 0, stream>>>(Sg, bm, Vh, AO, c * 4);
  }
  out_gemm<<<(ROWS / 64) * (INNER / 64), 256, 0, stream>>>(AO, wot, bo, (float*)d_out);
}

// Round 16
// 145.476 us; speedup vs baseline: 2.1919x; 1.3913x over previous
//
#include <hip/hip_runtime.h>

typedef __bf16 bf8 __attribute__((ext_vector_type(8)));
typedef float f4 __attribute__((ext_vector_type(4)));
typedef _Float16 h8 __attribute__((ext_vector_type(8)));
typedef _Float16 h2 __attribute__((ext_vector_type(2)));

// Problem constants (fixed by reference)
constexpr int BSZ = 2, NSEQ = 2048, DIM = 512, NH = 8, DH = 64, INNER = 512;
constexpr int ROWS = BSZ * NSEQ;          // 4096

// Workspace layout (bytes) — d_ws is >=268 MB (harness poison size)
constexpr size_t XB_OFF  = 0;                          // x cast bf16: 4 MB
constexpr size_t WQT_OFF = 4194304;                    // W_qkv^T bf16: 1.5 MB
constexpr size_t WOT_OFF = WQT_OFF + 1572864;          // W_out^T bf16: 0.5 MB
constexpr size_t Q_OFF   = WOT_OFF + 524288;           // Q/8 bf16 [16][2048][64]: 4 MB
constexpr size_t K_OFF   = Q_OFF + 4194304;            // K bf16: 4 MB
constexpr size_t V_OFF   = K_OFF + 4194304;            // V bf16: 4 MB
constexpr size_t AO_OFF  = V_OFF + 4194304;            // attn out bf16 [4096][512]: 4 MB
constexpr size_t SG_OFF  = AO_OFF + 4194304;           // S f16 [16][2048][2048]: 128 MB
constexpr size_t BM_OFF  = SG_OFF + 134217728;         // bmax f32 [16][2048][16]: 2 MB
// total ~152 MB

// ---------------- prep: cast x to bf16; transpose+cast W_qkv, W_out ----------------
__global__ __launch_bounds__(256) void prep_kernel(
    const float* __restrict__ x, const float* __restrict__ Wq, const float* __restrict__ Wo,
    __bf16* __restrict__ xb, __bf16* __restrict__ wqt, __bf16* __restrict__ wot) {
  int idx = blockIdx.x * 256 + threadIdx.x;
  if (idx < ROWS * DIM) xb[idx] = (__bf16)x[idx];
  if (idx < 3 * INNER * DIM) {            // wqt[n][k] = Wq[k][n]
    int n = idx >> 9, k = idx & 511;
    wqt[idx] = (__bf16)Wq[k * (3 * INNER) + n];
  }
  if (idx < INNER * DIM) {                // wot[n][k] = Wo[k][n]
    int n = idx >> 9, k = idx & 511;
    wot[idx] = (__bf16)Wo[k * DIM + n];
  }
}

// ---------------- kernel 1: qkv = x @ W_qkv -> Q/8,K,V.  128x128 tile, BK=64, ----
// T14 reg-staged LDS pipeline: issue loads for step k+1 before computing step k.
__global__ __launch_bounds__(256) void qkv_gemm(
    const __bf16* __restrict__ xb, const __bf16* __restrict__ wqt,
    __bf16* __restrict__ Qh, __bf16* __restrict__ Kh, __bf16* __restrict__ Vh) {
  __shared__ __bf16 Asm[128 * 64];          // byte = r*128 + (chbyte ^ ((r&7)<<4))
  __shared__ __bf16 Bsm[128 * 64];
  int bid = blockIdx.x;
  int bn = bid % 12, bm = bid / 12;         // 12 col-tiles x 32 row-tiles of 128
  int t = threadIdx.x, lane = t & 63, wid = t >> 6;
  int wy = wid >> 1, wx = wid & 1;
  int l15 = lane & 15, lg = lane >> 4;
  // staging geometry: thread t covers rows j*32+(t>>3), 16B chunk (t&7)
  int sr = t >> 3, sc = t & 7;
  const __bf16* Ag = xb  + (size_t)(bm * 128 + sr) * 512 + sc * 8;
  const __bf16* Bg = wqt + (size_t)(bn * 128 + sr) * 512 + sc * 8;
  int swz = (sc * 16) ^ ((sr & 7) << 4);    // (j*32 preserves r&7)
  bf8 ra[4], rb[4];
#pragma unroll
  for (int j = 0; j < 4; ++j) {
    ra[j] = *(const bf8*)(Ag + (size_t)(j * 32) * 512);
    rb[j] = *(const bf8*)(Bg + (size_t)(j * 32) * 512);
  }
  f4 acc[4][4];
#pragma unroll
  for (int mt = 0; mt < 4; ++mt)
#pragma unroll
    for (int nt = 0; nt < 4; ++nt) acc[mt][nt] = (f4){0.f, 0.f, 0.f, 0.f};

  for (int ks = 0; ks < 8; ++ks) {
    __syncthreads();                        // all waves done reading previous tile
#pragma unroll
    for (int j = 0; j < 4; ++j) {
      *(bf8*)((char*)Asm + (size_t)(j * 32 + sr) * 128 + swz) = ra[j];
      *(bf8*)((char*)Bsm + (size_t)(j * 32 + sr) * 128 + swz) = rb[j];
    }
    if (ks < 7) {                           // issue next-tile loads; they fly during MFMA
      const __bf16* Ag2 = Ag + (ks + 1) * 64;
      const __bf16* Bg2 = Bg + (ks + 1) * 64;
#pragma unroll
      for (int j = 0; j < 4; ++j) {
        ra[j] = *(const bf8*)(Ag2 + (size_t)(j * 32) * 512);
        rb[j] = *(const bf8*)(Bg2 + (size_t)(j * 32) * 512);
      }
    }
    __syncthreads();                        // LDS tile ready (lgkm drained)
#pragma unroll
    for (int kk = 0; kk < 2; ++kk) {
      bf8 af[4], bg[4];
#pragma unroll
      for (int mt = 0; mt < 4; ++mt) {
        int r = wy * 64 + mt * 16 + l15;
        af[mt] = *(const bf8*)((const char*)Asm + (size_t)r * 128 +
                               ((kk * 64 + lg * 16) ^ ((r & 7) << 4)));
      }
#pragma unroll
      for (int nt = 0; nt < 4; ++nt) {
        int r = wx * 64 + nt * 16 + l15;
        bg[nt] = *(const bf8*)((const char*)Bsm + (size_t)r * 128 +
                               ((kk * 64 + lg * 16) ^ ((r & 7) << 4)));
      }
#pragma unroll
      for (int mt = 0; mt < 4; ++mt)
#pragma unroll
        for (int nt = 0; nt < 4; ++nt)
          acc[mt][nt] = __builtin_amdgcn_mfma_f32_16x16x32_bf16(af[mt], bg[nt], acc[mt][nt], 0, 0, 0);
    }
  }
  // epilogue: scatter into Q/8, K, V
#pragma unroll
  for (int mt = 0; mt < 4; ++mt)
#pragma unroll
    for (int nt = 0; nt < 4; ++nt) {
      int col = bn * 128 + wx * 64 + nt * 16 + l15;
      int which = col >> 9;                  // 0=q 1=k 2=v
      int inner = col & 511;
      int h = inner >> 6, d = inner & 63;
      __bf16* dst = which == 0 ? Qh : (which == 1 ? Kh : Vh);
      float scale = which == 0 ? 0.125f : 1.0f;
#pragma unroll
      for (int i = 0; i < 4; ++i) {
        int row = bm * 128 + wy * 64 + mt * 16 + lg * 4 + i;
        int b = row >> 11, n = row & 2047;
        dst[(((size_t)(b * 8 + h)) * 2048 + n) * 64 + d] = (__bf16)(acc[mt][nt][i] * scale);
      }
    }
}

// ---------------- kernel 2a: S = (Q/8) @ K^T + per-block row-max, all 16 heads ----
// K-tile LDS-staged once per block (shared by 4 waves); LDS reused for store repack.
// Grid 4096, XCD-swizzled so each XCD works on ~2 heads (K/Q panels stay in its L2).
__global__ __launch_bounds__(256) void qk_gemm(
    const __bf16* __restrict__ Qh, const __bf16* __restrict__ Kh,
    _Float16* __restrict__ Sg, float* __restrict__ bmax) {
  __shared__ char lds[32768];               // [0,16K): K-tile; later: ct[4][32][128]
  int bid = blockIdx.x;
  int lin = (bid & 7) * 512 + (bid >> 3);   // bijective XCD swizzle (4096 % 8 == 0)
  int bh = lin >> 8;                        // head 0..15
  int rt = (lin >> 4) & 15;                 // q row-tile (128)
  int colt = lin & 15;                      // k col-tile (128)
  int t = threadIdx.x, lane = t & 63, wid = t >> 6;
  int l15 = lane & 15, lg = lane >> 4;

  // stage K-tile [128 rows][64 dims] cooperatively, swizzled (rule #21 both-sides)
  {
    int sr = t >> 3, sc = t & 7;            // 32 rows/pass, full 128B rows coalesced
    const __bf16* Kg = Kh + ((size_t)bh * 2048 + colt * 128 + sr) * 64 + sc * 8;
    bf8 k0 = *(const bf8*)(Kg);
    bf8 k1 = *(const bf8*)(Kg + 32 * 64);
    bf8 k2 = *(const bf8*)(Kg + 64 * 64);
    bf8 k3 = *(const bf8*)(Kg + 96 * 64);
    int swz = (sc * 16) ^ ((sr & 7) << 4);  // +32j preserves r&7
    *(bf8*)(lds + (size_t)sr * 128 + swz) = k0;
    *(bf8*)(lds + (size_t)(sr + 32) * 128 + swz) = k1;
    *(bf8*)(lds + (size_t)(sr + 64) * 128 + swz) = k2;
    *(bf8*)(lds + (size_t)(sr + 96) * 128 + swz) = k3;
  }
  const __bf16* Qp = Qh + ((size_t)bh * 2048 + rt * 128 + wid * 32) * 64;
  bf8 aA0 = *(const bf8*)(Qp + l15 * 64 + lg * 8);
  bf8 aA1 = *(const bf8*)(Qp + l15 * 64 + 32 + lg * 8);
  bf8 aB0 = *(const bf8*)(Qp + (16 + l15) * 64 + lg * 8);
  bf8 aB1 = *(const bf8*)(Qp + (16 + l15) * 64 + 32 + lg * 8);
  __syncthreads();                          // K-tile ready

  f4 acc[2][8];
#pragma unroll
  for (int s = 0; s < 2; ++s)
#pragma unroll
    for (int j = 0; j < 8; ++j) acc[s][j] = (f4){0.f, 0.f, 0.f, 0.f};
#pragma unroll
  for (int ctj = 0; ctj < 8; ++ctj) {
    int r = ctj * 16 + l15;
    const char* kb = lds + (size_t)r * 128;
    int sw = (r & 7) << 4;
    bf8 b0 = *(const bf8*)(kb + ((lg * 16) ^ sw));        // dims lg*8..+8
    bf8 b1 = *(const bf8*)(kb + ((64 + lg * 16) ^ sw));   // dims 32+lg*8..+8
    acc[0][ctj] = __builtin_amdgcn_mfma_f32_16x16x32_bf16(aA0, b0, acc[0][ctj], 0, 0, 0);
    acc[0][ctj] = __builtin_amdgcn_mfma_f32_16x16x32_bf16(aA1, b1, acc[0][ctj], 0, 0, 0);
    acc[1][ctj] = __builtin_amdgcn_mfma_f32_16x16x32_bf16(aB0, b0, acc[1][ctj], 0, 0, 0);
    acc[1][ctj] = __builtin_amdgcn_mfma_f32_16x16x32_bf16(aB1, b1, acc[1][ctj], 0, 0, 0);
  }
  // per-block row-max (for sparse_pv's filter)
#pragma unroll
  for (int s = 0; s < 2; ++s)
#pragma unroll
    for (int i = 0; i < 4; ++i) {
      float rm = acc[s][0][i];
#pragma unroll
      for (int ctj = 1; ctj < 8; ++ctj) rm = fmaxf(rm, acc[s][ctj][i]);
#pragma unroll
      for (int o = 1; o < 16; o <<= 1) rm = fmaxf(rm, __shfl_xor(rm, o));
      if (l15 == 0) {
        int row = rt * 128 + wid * 32 + s * 16 + lg * 4 + i;
        bmax[((size_t)bh * 2048 + row) * 16 + colt] = rm;
      }
    }
  __syncthreads();                          // all waves done reading K-tile; reuse LDS
  _Float16 (*ct)[32][128] = (_Float16(*)[32][128])lds;
#pragma unroll
  for (int s = 0; s < 2; ++s)
#pragma unroll
    for (int ctj = 0; ctj < 8; ++ctj)
#pragma unroll
      for (int i = 0; i < 4; ++i) {
        int row = s * 16 + lg * 4 + i;
        int col = ctj * 16 + l15;
        ct[wid][row][col ^ (((row >> 2) & 3) << 4)] = (_Float16)acc[s][ctj][i];
      }
  int r4 = lane >> 4, ch = lane & 15;       // wave-private region: no barrier needed
  size_t srow0 = (size_t)bh * 2048 + rt * 128 + wid * 32;
#pragma unroll
  for (int it = 0; it < 8; ++it) {
    int r = it * 4 + r4;
    h8 v = *(const h8*)&ct[wid][r][(ch * 8) ^ (((r >> 2) & 3) << 4)];
    *(h8*)&Sg[(srow0 + r) * 2048 + colt * 128 + ch * 8] = v;
  }
}

// ---------------- kernel 2b: bmax-filtered sparsemax + sparse PV, one wave/row ----
__global__ __launch_bounds__(512, 8) void sparse_pv(
    const _Float16* __restrict__ Sg, const float* __restrict__ bmax,
    const __bf16* __restrict__ Vh, __bf16* __restrict__ AO) {
  __shared__ float candv[8][64];            // 2 KB
  __shared__ int   candj[8][64];            // 2 KB
  int lane = threadIdx.x & 63, wid = threadIdx.x >> 6;   // 8 waves
  int rowid = blockIdx.x * 8 + wid;         // 0..32767
  int bh = rowid >> 11, n = rowid & 2047;
  const _Float16* Srow = Sg + ((size_t)bh * 2048 + n) * 2048;
  const float* bmr = bmax + ((size_t)bh * 2048 + n) * 16;
  const __bf16* Vp = Vh + (size_t)bh * 2048 * 64;

  float bmv[16];
  *(f4*)&bmv[0]  = *(const f4*)&bmr[0];
  *(f4*)&bmv[4]  = *(const f4*)&bmr[4];
  *(f4*)&bmv[8]  = *(const f4*)&bmr[8];
  *(f4*)&bmv[12] = *(const f4*)&bmr[12];
  float gmax = bmv[0];
#pragma unroll
  for (int ct = 1; ct < 16; ++ct) gmax = fmaxf(gmax, bmv[ct]);
  // tau* >= max-1; 0.02 slack covers f16 rounding of stored S vs f32 bmax.
  float tau0 = gmax - 1.02f;

  candv[wid][lane] = -1e30f;                // prefill so unwritten slots are inert
  candj[wid][lane] = 0;
  int base = 0; bool ovf = false;
#pragma unroll
  for (int ct = 0; ct < 16; ++ct) {
    if (bmv[ct] > tau0) {                   // row-uniform -> wave-uniform
      h2 zz = *(const h2*)&Srow[ct * 128 + lane * 2];
      float z0 = (float)zz[0], z1 = (float)zz[1];
      int m = (z0 > tau0 ? 1 : 0) | (z1 > tau0 ? 2 : 0);
      int pc = __popc((unsigned)m);
      int off = pc;
#pragma unroll
      for (int d = 1; d < 64; d <<= 1) {
        int tt = __shfl_up(off, d);
        if (lane >= d) off += tt;
      }
      int tot = __shfl(off, 63);
      off -= pc;
      if (base + tot <= 64) {
        int slot = base + off;
        if (m & 1) { candv[wid][slot] = z0; candj[wid][slot] = ct * 128 + lane * 2; ++slot; }
        if (m & 2) { candv[wid][slot] = z1; candj[wid][slot] = ct * 128 + lane * 2 + 1; }
      } else ovf = true;
      base += tot;
    }
  }
  int total = base;
  float tau = tau0, acc_o = 0.f;
  if (!ovf) {
    if (total <= 16) {
      // register path: 4 broadcast b128 loads, pure-VALU Michelot, branchless gather
      f4 cv0 = *(const f4*)&candv[wid][0];
      f4 cv1 = *(const f4*)&candv[wid][4];
      f4 cv2 = *(const f4*)&candv[wid][8];
      f4 cv3 = *(const f4*)&candv[wid][12];
      float cprev = -1.0f;
      for (int it = 0; it < 20; ++it) {
        float s = 0.f, c = 0.f;
#pragma unroll
        for (int i = 0; i < 4; ++i) {
          if (cv0[i] > tau) { s += cv0[i]; c += 1.f; }
          if (cv1[i] > tau) { s += cv1[i]; c += 1.f; }
          if (cv2[i] > tau) { s += cv2[i]; c += 1.f; }
          if (cv3[i] > tau) { s += cv3[i]; c += 1.f; }
        }
        if (c == cprev) break;
        tau = (s - 1.0f) / c; cprev = c;
      }
      const __bf16* vb = Vp + lane;
#pragma unroll
      for (int jc = 0; jc < 4; ++jc) {
        f4 cj = jc == 0 ? cv0 : (jc == 1 ? cv1 : (jc == 2 ? cv2 : cv3));
        int j0 = candj[wid][jc * 4 + 0];
        int j1 = candj[wid][jc * 4 + 1];
        int j2 = candj[wid][jc * 4 + 2];
        int j3 = candj[wid][jc * 4 + 3];
        acc_o += fmaxf(cj[0] - tau, 0.f) * (float)vb[(size_t)j0 * 64];
        acc_o += fmaxf(cj[1] - tau, 0.f) * (float)vb[(size_t)j1 * 64];
        acc_o += fmaxf(cj[2] - tau, 0.f) * (float)vb[(size_t)j2 * 64];
        acc_o += fmaxf(cj[3] - tau, 0.f) * (float)vb[(size_t)j3 * 64];
      }
    } else {
      // mid path: Michelot on 1 candidate per lane (butterfly reduce)
      float v = candv[wid][lane];
      bool valid = lane < total;
      float cprev = -1.0f;
      for (int it = 0; it < 24; ++it) {
        bool in = valid && (v > tau);
        float s = in ? v : 0.f, c = in ? 1.f : 0.f;
#pragma unroll
        for (int o = 32; o; o >>= 1) { s += __shfl_xor(s, o); c += __shfl_xor(c, o); }
        if (c == cprev) break;
        tau = (s - 1.0f) / c; cprev = c;
      }
      for (int j = 0; j < total; ++j) {
        float p = candv[wid][j] - tau;
        if (p > 0.f) {
          int idx = candj[wid][j];
          acc_o += p * (float)Vp[(size_t)idx * 64 + lane];
        }
      }
    }
  } else {
    // fallback (rare): read full row, full-register Michelot from tau0 + ballot gather
    h8 zc[4];
#pragma unroll
    for (int r = 0; r < 4; ++r)
      zc[r] = *(const h8*)&Srow[r * 512 + lane * 8];
    float cprev = -1.0f;
    for (int it = 0; it < 48; ++it) {
      float s = 0.f, c = 0.f;
#pragma unroll
      for (int r = 0; r < 4; ++r)
#pragma unroll
        for (int i = 0; i < 8; ++i) {
          float zz = (float)zc[r][i];
          if (zz > tau) { s += zz; c += 1.f; }
        }
#pragma unroll
      for (int o = 32; o; o >>= 1) { s += __shfl_xor(s, o); c += __shfl_xor(c, o); }
      if (c == cprev) break;
      tau = (s - 1.0f) / c; cprev = c;
    }
#pragma unroll
    for (int r = 0; r < 4; ++r)
#pragma unroll
      for (int i = 0; i < 8; ++i) {
        float p = (float)zc[r][i] - tau;
        unsigned long long m = __ballot(p > 0.f);
        while (m) {
          int src = __ffsll((long long)m) - 1;
          m &= m - 1;
          float pj = __shfl(p, src);
          int j = r * 512 + src * 8 + i;
          acc_o += pj * (float)Vp[(size_t)j * 64 + lane];
        }
      }
  }
  int rowg = (bh >> 3) * 2048 + n;          // [B][N] row
  AO[(size_t)rowg * 512 + (bh & 7) * 64 + lane] = (__bf16)acc_o;
}

// ---------------- kernel 3: out = AO @ W_out + b_out.  128x128 tile, T14 pipeline ----
__global__ __launch_bounds__(256) void out_gemm(
    const __bf16* __restrict__ A, const __bf16* __restrict__ wot,
    const float* __restrict__ bias, float* __restrict__ out) {
  __shared__ __bf16 Asm[128 * 64];
  __shared__ __bf16 Bsm[128 * 64];
  int bid = blockIdx.x;
  int bn = bid & 3, bm = bid >> 2;          // 4 col-tiles x 32 row-tiles of 128
  int t = threadIdx.x, lane = t & 63, wid = t >> 6;
  int wy = wid >> 1, wx = wid & 1;
  int l15 = lane & 15, lg = lane >> 4;
  int sr = t >> 3, sc = t & 7;
  const __bf16* Ag = A   + (size_t)(bm * 128 + sr) * 512 + sc * 8;
  const __bf16* Bg = wot + (size_t)(bn * 128 + sr) * 512 + sc * 8;
  int swz = (sc * 16) ^ ((sr & 7) << 4);
  bf8 ra[4], rb[4];
#pragma unroll
  for (int j = 0; j < 4; ++j) {
    ra[j] = *(const bf8*)(Ag + (size_t)(j * 32) * 512);
    rb[j] = *(const bf8*)(Bg + (size_t)(j * 32) * 512);
  }
  f4 acc[4][4];
#pragma unroll
  for (int mt = 0; mt < 4; ++mt)
#pragma unroll
    for (int nt = 0; nt < 4; ++nt) acc[mt][nt] = (f4){0.f, 0.f, 0.f, 0.f};

  for (int ks = 0; ks < 8; ++ks) {
    __syncthreads();
#pragma unroll
    for (int j = 0; j < 4; ++j) {
      *(bf8*)((char*)Asm + (size_t)(j * 32 + sr) * 128 + swz) = ra[j];
      *(bf8*)((char*)Bsm + (size_t)(j * 32 + sr) * 128 + swz) = rb[j];
    }
    if (ks < 7) {
      const __bf16* Ag2 = Ag + (ks + 1) * 64;
      const __bf16* Bg2 = Bg + (ks + 1) * 64;
#pragma unroll
      for (int j = 0; j < 4; ++j) {
        ra[j] = *(const bf8*)(Ag2 + (size_t)(j * 32) * 512);
        rb[j] = *(const bf8*)(Bg2 + (size_t)(j * 32) * 512);
      }
    }
    __syncthreads();
#pragma unroll
    for (int kk = 0; kk < 2; ++kk) {
      bf8 af[4], bg[4];
#pragma unroll
      for (int mt = 0; mt < 4; ++mt) {
        int r = wy * 64 + mt * 16 + l15;
        af[mt] = *(const bf8*)((const char*)Asm + (size_t)r * 128 +
                               ((kk * 64 + lg * 16) ^ ((r & 7) << 4)));
      }
#pragma unroll
      for (int nt = 0; nt < 4; ++nt) {
        int r = wx * 64 + nt * 16 + l15;
        bg[nt] = *(const bf8*)((const char*)Bsm + (size_t)r * 128 +
                               ((kk * 64 + lg * 16) ^ ((r & 7) << 4)));
      }
#pragma unroll
      for (int mt = 0; mt < 4; ++mt)
#pragma unroll
        for (int nt = 0; nt < 4; ++nt)
          acc[mt][nt] = __builtin_amdgcn_mfma_f32_16x16x32_bf16(af[mt], bg[nt], acc[mt][nt], 0, 0, 0);
    }
  }
#pragma unroll
  for (int mt = 0; mt < 4; ++mt)
#pragma unroll
    for (int nt = 0; nt < 4; ++nt) {
      int col = bn * 128 + wx * 64 + nt * 16 + l15;
      float bv = bias[col];
#pragma unroll
      for (int i = 0; i < 4; ++i) {
        int row = bm * 128 + wy * 64 + mt * 16 + lg * 4 + i;
        out[(size_t)row * 512 + col] = acc[mt][nt][i] + bv;
      }
    }
}

extern "C" void kernel_launch(void* const* d_in, const int* in_sizes, int n_in,
                              void* d_out, int out_size, void* d_ws, size_t ws_size,
                              hipStream_t stream) {
  const float* x  = (const float*)d_in[0];
  const float* Wq = (const float*)d_in[1];
  const float* Wo = (const float*)d_in[2];
  const float* bo = (const float*)d_in[3];
  char* ws = (char*)d_ws;
  __bf16* xb  = (__bf16*)(ws + XB_OFF);
  __bf16* wqt = (__bf16*)(ws + WQT_OFF);
  __bf16* wot = (__bf16*)(ws + WOT_OFF);
  __bf16* Qh  = (__bf16*)(ws + Q_OFF);
  __bf16* Kh  = (__bf16*)(ws + K_OFF);
  __bf16* Vh  = (__bf16*)(ws + V_OFF);
  __bf16* AO  = (__bf16*)(ws + AO_OFF);
  _Float16* Sg = (_Float16*)(ws + SG_OFF);
  float* bm = (float*)(ws + BM_OFF);

  prep_kernel<<<(ROWS * DIM) / 256, 256, 0, stream>>>(x, Wq, Wo, xb, wqt, wot);
  qkv_gemm<<<32 * 12, 256, 0, stream>>>(xb, wqt, Qh, Kh, Vh);
  qk_gemm<<<4096, 256, 0, stream>>>(Qh, Kh, Sg, bm);
  sparse_pv<<<4096, 512, 0, stream>>>(Sg, bm, Vh, AO);
  out_gemm<<<128, 256, 0, stream>>>(AO, wot, bo, (float*)d_out);
}

// Round 17
// 133.230 us; speedup vs baseline: 2.3934x; 1.0919x over previous
//
#include <hip/hip_runtime.h>

typedef __bf16 bf8 __attribute__((ext_vector_type(8)));
typedef float f4 __attribute__((ext_vector_type(4)));
typedef _Float16 h8 __attribute__((ext_vector_type(8)));
typedef _Float16 h2 __attribute__((ext_vector_type(2)));

// Problem constants (fixed by reference)
constexpr int BSZ = 2, NSEQ = 2048, DIM = 512, NH = 8, DH = 64, INNER = 512;
constexpr int ROWS = BSZ * NSEQ;          // 4096

// Workspace layout (bytes) — d_ws is >=268 MB (harness poison size)
constexpr size_t XB_OFF  = 0;                          // x cast bf16: 4 MB
constexpr size_t WQT_OFF = 4194304;                    // W_qkv^T bf16: 1.5 MB
constexpr size_t WOT_OFF = WQT_OFF + 1572864;          // W_out^T bf16: 0.5 MB
constexpr size_t Q_OFF   = WOT_OFF + 524288;           // Q/8 bf16 [16][2048][64]: 4 MB
constexpr size_t K_OFF   = Q_OFF + 4194304;            // K bf16: 4 MB
constexpr size_t V_OFF   = K_OFF + 4194304;            // V bf16: 4 MB
constexpr size_t AO_OFF  = V_OFF + 4194304;            // attn out bf16 [4096][512]: 4 MB
constexpr size_t SG_OFF  = AO_OFF + 4194304;           // S f16 [16][2048][2048]: 128 MB
constexpr size_t BM_OFF  = SG_OFF + 134217728;         // bmax f32 [16][2048][16]: 2 MB
// total ~152 MB

// ---------------- prep: cast x to bf16; transpose+cast W_qkv, W_out ----------------
__global__ __launch_bounds__(256) void prep_kernel(
    const float* __restrict__ x, const float* __restrict__ Wq, const float* __restrict__ Wo,
    __bf16* __restrict__ xb, __bf16* __restrict__ wqt, __bf16* __restrict__ wot) {
  int idx = blockIdx.x * 256 + threadIdx.x;
  if (idx < ROWS * DIM) xb[idx] = (__bf16)x[idx];
  if (idx < 3 * INNER * DIM) {            // wqt[n][k] = Wq[k][n]
    int n = idx >> 9, k = idx & 511;
    wqt[idx] = (__bf16)Wq[k * (3 * INNER) + n];
  }
  if (idx < INNER * DIM) {                // wot[n][k] = Wo[k][n]
    int n = idx >> 9, k = idx & 511;
    wot[idx] = (__bf16)Wo[k * DIM + n];
  }
}

// ---------------- kernel 1: qkv = x @ W_qkv -> Q/8,K,V.  128x128 tile, BK=64, ----
// T14 reg-staged LDS pipeline: issue loads for step k+1 before computing step k.
__global__ __launch_bounds__(256) void qkv_gemm(
    const __bf16* __restrict__ xb, const __bf16* __restrict__ wqt,
    __bf16* __restrict__ Qh, __bf16* __restrict__ Kh, __bf16* __restrict__ Vh) {
  __shared__ __bf16 Asm[128 * 64];          // byte = r*128 + (chbyte ^ ((r&7)<<4))
  __shared__ __bf16 Bsm[128 * 64];
  int bid = blockIdx.x;
  int bn = bid % 12, bm = bid / 12;         // 12 col-tiles x 32 row-tiles of 128
  int t = threadIdx.x, lane = t & 63, wid = t >> 6;
  int wy = wid >> 1, wx = wid & 1;
  int l15 = lane & 15, lg = lane >> 4;
  // staging geometry: thread t covers rows j*32+(t>>3), 16B chunk (t&7)
  int sr = t >> 3, sc = t & 7;
  const __bf16* Ag = xb  + (size_t)(bm * 128 + sr) * 512 + sc * 8;
  const __bf16* Bg = wqt + (size_t)(bn * 128 + sr) * 512 + sc * 8;
  int swz = (sc * 16) ^ ((sr & 7) << 4);    // (j*32 preserves r&7)
  bf8 ra[4], rb[4];
#pragma unroll
  for (int j = 0; j < 4; ++j) {
    ra[j] = *(const bf8*)(Ag + (size_t)(j * 32) * 512);
    rb[j] = *(const bf8*)(Bg + (size_t)(j * 32) * 512);
  }
  f4 acc[4][4];
#pragma unroll
  for (int mt = 0; mt < 4; ++mt)
#pragma unroll
    for (int nt = 0; nt < 4; ++nt) acc[mt][nt] = (f4){0.f, 0.f, 0.f, 0.f};

  for (int ks = 0; ks < 8; ++ks) {
    __syncthreads();                        // all waves done reading previous tile
#pragma unroll
    for (int j = 0; j < 4; ++j) {
      *(bf8*)((char*)Asm + (size_t)(j * 32 + sr) * 128 + swz) = ra[j];
      *(bf8*)((char*)Bsm + (size_t)(j * 32 + sr) * 128 + swz) = rb[j];
    }
    if (ks < 7) {                           // issue next-tile loads; they fly during MFMA
      const __bf16* Ag2 = Ag + (ks + 1) * 64;
      const __bf16* Bg2 = Bg + (ks + 1) * 64;
#pragma unroll
      for (int j = 0; j < 4; ++j) {
        ra[j] = *(const bf8*)(Ag2 + (size_t)(j * 32) * 512);
        rb[j] = *(const bf8*)(Bg2 + (size_t)(j * 32) * 512);
      }
    }
    __syncthreads();                        // LDS tile ready (lgkm drained)
#pragma unroll
    for (int kk = 0; kk < 2; ++kk) {
      bf8 af[4], bg[4];
#pragma unroll
      for (int mt = 0; mt < 4; ++mt) {
        int r = wy * 64 + mt * 16 + l15;
        af[mt] = *(const bf8*)((const char*)Asm + (size_t)r * 128 +
                               ((kk * 64 + lg * 16) ^ ((r & 7) << 4)));
      }
#pragma unroll
      for (int nt = 0; nt < 4; ++nt) {
        int r = wx * 64 + nt * 16 + l15;
        bg[nt] = *(const bf8*)((const char*)Bsm + (size_t)r * 128 +
                               ((kk * 64 + lg * 16) ^ ((r & 7) << 4)));
      }
#pragma unroll
      for (int mt = 0; mt < 4; ++mt)
#pragma unroll
        for (int nt = 0; nt < 4; ++nt)
          acc[mt][nt] = __builtin_amdgcn_mfma_f32_16x16x32_bf16(af[mt], bg[nt], acc[mt][nt], 0, 0, 0);
    }
  }
  // epilogue: scatter into Q/8, K, V
#pragma unroll
  for (int mt = 0; mt < 4; ++mt)
#pragma unroll
    for (int nt = 0; nt < 4; ++nt) {
      int col = bn * 128 + wx * 64 + nt * 16 + l15;
      int which = col >> 9;                  // 0=q 1=k 2=v
      int inner = col & 511;
      int h = inner >> 6, d = inner & 63;
      __bf16* dst = which == 0 ? Qh : (which == 1 ? Kh : Vh);
      float scale = which == 0 ? 0.125f : 1.0f;
#pragma unroll
      for (int i = 0; i < 4; ++i) {
        int row = bm * 128 + wy * 64 + mt * 16 + lg * 4 + i;
        int b = row >> 11, n = row & 2047;
        dst[(((size_t)(b * 8 + h)) * 2048 + n) * 64 + d] = (__bf16)(acc[mt][nt][i] * scale);
      }
    }
}

// ---------------- kernel 2a: S = (Q/8) @ K^T + per-block row-max, all 16 heads ----
// K-tile LDS-staged once per block (shared by 4 waves); LDS reused for store repack.
// Grid 4096, XCD-swizzled so each XCD works on ~2 heads (K/Q panels stay in its L2).
__global__ __launch_bounds__(256) void qk_gemm(
    const __bf16* __restrict__ Qh, const __bf16* __restrict__ Kh,
    _Float16* __restrict__ Sg, float* __restrict__ bmax) {
  __shared__ char lds[32768];               // [0,16K): K-tile; later: ct[4][32][128]
  int bid = blockIdx.x;
  int lin = (bid & 7) * 512 + (bid >> 3);   // bijective XCD swizzle (4096 % 8 == 0)
  int bh = lin >> 8;                        // head 0..15
  int rt = (lin >> 4) & 15;                 // q row-tile (128)
  int colt = lin & 15;                      // k col-tile (128)
  int t = threadIdx.x, lane = t & 63, wid = t >> 6;
  int l15 = lane & 15, lg = lane >> 4;

  // stage K-tile [128 rows][64 dims] cooperatively, swizzled (rule #21 both-sides)
  {
    int sr = t >> 3, sc = t & 7;            // 32 rows/pass, full 128B rows coalesced
    const __bf16* Kg = Kh + ((size_t)bh * 2048 + colt * 128 + sr) * 64 + sc * 8;
    bf8 k0 = *(const bf8*)(Kg);
    bf8 k1 = *(const bf8*)(Kg + 32 * 64);
    bf8 k2 = *(const bf8*)(Kg + 64 * 64);
    bf8 k3 = *(const bf8*)(Kg + 96 * 64);
    int swz = (sc * 16) ^ ((sr & 7) << 4);  // +32j preserves r&7
    *(bf8*)(lds + (size_t)sr * 128 + swz) = k0;
    *(bf8*)(lds + (size_t)(sr + 32) * 128 + swz) = k1;
    *(bf8*)(lds + (size_t)(sr + 64) * 128 + swz) = k2;
    *(bf8*)(lds + (size_t)(sr + 96) * 128 + swz) = k3;
  }
  const __bf16* Qp = Qh + ((size_t)bh * 2048 + rt * 128 + wid * 32) * 64;
  bf8 aA0 = *(const bf8*)(Qp + l15 * 64 + lg * 8);
  bf8 aA1 = *(const bf8*)(Qp + l15 * 64 + 32 + lg * 8);
  bf8 aB0 = *(const bf8*)(Qp + (16 + l15) * 64 + lg * 8);
  bf8 aB1 = *(const bf8*)(Qp + (16 + l15) * 64 + 32 + lg * 8);
  __syncthreads();                          // K-tile ready

  f4 acc[2][8];
#pragma unroll
  for (int s = 0; s < 2; ++s)
#pragma unroll
    for (int j = 0; j < 8; ++j) acc[s][j] = (f4){0.f, 0.f, 0.f, 0.f};
#pragma unroll
  for (int ctj = 0; ctj < 8; ++ctj) {
    int r = ctj * 16 + l15;
    const char* kb = lds + (size_t)r * 128;
    int sw = (r & 7) << 4;
    bf8 b0 = *(const bf8*)(kb + ((lg * 16) ^ sw));        // dims lg*8..+8
    bf8 b1 = *(const bf8*)(kb + ((64 + lg * 16) ^ sw));   // dims 32+lg*8..+8
    acc[0][ctj] = __builtin_amdgcn_mfma_f32_16x16x32_bf16(aA0, b0, acc[0][ctj], 0, 0, 0);
    acc[0][ctj] = __builtin_amdgcn_mfma_f32_16x16x32_bf16(aA1, b1, acc[0][ctj], 0, 0, 0);
    acc[1][ctj] = __builtin_amdgcn_mfma_f32_16x16x32_bf16(aB0, b0, acc[1][ctj], 0, 0, 0);
    acc[1][ctj] = __builtin_amdgcn_mfma_f32_16x16x32_bf16(aB1, b1, acc[1][ctj], 0, 0, 0);
  }
  // per-block row-max (for sparse_pv's filter)
#pragma unroll
  for (int s = 0; s < 2; ++s)
#pragma unroll
    for (int i = 0; i < 4; ++i) {
      float rm = acc[s][0][i];
#pragma unroll
      for (int ctj = 1; ctj < 8; ++ctj) rm = fmaxf(rm, acc[s][ctj][i]);
#pragma unroll
      for (int o = 1; o < 16; o <<= 1) rm = fmaxf(rm, __shfl_xor(rm, o));
      if (l15 == 0) {
        int row = rt * 128 + wid * 32 + s * 16 + lg * 4 + i;
        bmax[((size_t)bh * 2048 + row) * 16 + colt] = rm;
      }
    }
  __syncthreads();                          // all waves done reading K-tile; reuse LDS
  _Float16 (*ct)[32][128] = (_Float16(*)[32][128])lds;
#pragma unroll
  for (int s = 0; s < 2; ++s)
#pragma unroll
    for (int ctj = 0; ctj < 8; ++ctj)
#pragma unroll
      for (int i = 0; i < 4; ++i) {
        int row = s * 16 + lg * 4 + i;
        int col = ctj * 16 + l15;
        ct[wid][row][col ^ (((row >> 2) & 3) << 4)] = (_Float16)acc[s][ctj][i];
      }
  int r4 = lane >> 4, ch = lane & 15;       // wave-private region: no barrier needed
  size_t srow0 = (size_t)bh * 2048 + rt * 128 + wid * 32;
#pragma unroll
  for (int it = 0; it < 8; ++it) {
    int r = it * 4 + r4;
    h8 v = *(const h8*)&ct[wid][r][(ch * 8) ^ (((r >> 2) & 3) << 4)];
    *(h8*)&Sg[(srow0 + r) * 2048 + colt * 128 + ch * 8] = v;
  }
}

// ---------------- kernel 2b: bmax-filtered sparsemax + sparse PV, one wave/row ----
// Ballot-based compaction (no shfl_up scan); 32-cand register path; ballot gather mid.
__global__ __launch_bounds__(512, 8) void sparse_pv(
    const _Float16* __restrict__ Sg, const float* __restrict__ bmax,
    const __bf16* __restrict__ Vh, __bf16* __restrict__ AO) {
  __shared__ float candv[8][64];            // 2 KB
  __shared__ int   candj[8][64];            // 2 KB
  int lane = threadIdx.x & 63, wid = threadIdx.x >> 6;   // 8 waves
  int rowid = blockIdx.x * 8 + wid;         // 0..32767
  int bh = rowid >> 11, n = rowid & 2047;
  const _Float16* Srow = Sg + ((size_t)bh * 2048 + n) * 2048;
  const float* bmr = bmax + ((size_t)bh * 2048 + n) * 16;
  const __bf16* Vp = Vh + (size_t)bh * 2048 * 64;

  float bmv[16];
  *(f4*)&bmv[0]  = *(const f4*)&bmr[0];
  *(f4*)&bmv[4]  = *(const f4*)&bmr[4];
  *(f4*)&bmv[8]  = *(const f4*)&bmr[8];
  *(f4*)&bmv[12] = *(const f4*)&bmr[12];
  float gmax = bmv[0];
#pragma unroll
  for (int ct = 1; ct < 16; ++ct) gmax = fmaxf(gmax, bmv[ct]);
  // tau* >= max-1; 0.02 slack covers f16 rounding of stored S vs f32 bmax.
  float tau0 = gmax - 1.02f;

  candv[wid][lane] = -1e30f;                // prefill so unwritten slots are inert
  candj[wid][lane] = 0;
  unsigned long long lmask = (1ULL << lane) - 1;   // lower-lane mask
  int base = 0; bool ovf = false;
#pragma unroll
  for (int ct = 0; ct < 16; ++ct) {
    if (bmv[ct] > tau0) {                   // row-uniform -> wave-uniform
      h2 zz = *(const h2*)&Srow[ct * 128 + lane * 2];
      float z0 = (float)zz[0], z1 = (float)zz[1];
      bool c0 = z0 > tau0, c1 = z1 > tau0;
      unsigned long long b0 = __ballot(c0), b1 = __ballot(c1);
      int n0 = __popcll(b0);
      int tot = n0 + __popcll(b1);
      if (base + tot <= 64) {
        if (c0) {
          int s0 = base + __popcll(b0 & lmask);
          candv[wid][s0] = z0; candj[wid][s0] = ct * 128 + lane * 2;
        }
        if (c1) {
          int s1 = base + n0 + __popcll(b1 & lmask);
          candv[wid][s1] = z1; candj[wid][s1] = ct * 128 + lane * 2 + 1;
        }
      } else ovf = true;
      base += tot;
    }
  }
  int total = base;
  float tau = tau0, acc_o = 0.f;
  if (!ovf) {
    if (total <= 32) {
      // register path: 8 broadcast b128 loads, pure-VALU Michelot, branchless gather
      f4 cv[8];
#pragma unroll
      for (int g = 0; g < 8; ++g) cv[g] = *(const f4*)&candv[wid][g * 4];
      float cprev = -1.0f;
      for (int it = 0; it < 20; ++it) {
        float s = 0.f, c = 0.f;
#pragma unroll
        for (int g = 0; g < 8; ++g)
#pragma unroll
          for (int i = 0; i < 4; ++i) {
            float v = cv[g][i];
            if (v > tau) { s += v; c += 1.f; }
          }
        if (c == cprev) break;
        tau = (s - 1.0f) / c; cprev = c;
      }
      // branchless gather: dead slots (candj=0) hit V row 0 -> L1 broadcast, p<=0
      const __bf16* vb = Vp + lane;
#pragma unroll
      for (int g = 0; g < 8; ++g) {
        int j0 = candj[wid][g * 4 + 0];
        int j1 = candj[wid][g * 4 + 1];
        int j2 = candj[wid][g * 4 + 2];
        int j3 = candj[wid][g * 4 + 3];
        acc_o += fmaxf(cv[g][0] - tau, 0.f) * (float)vb[(size_t)j0 * 64];
        acc_o += fmaxf(cv[g][1] - tau, 0.f) * (float)vb[(size_t)j1 * 64];
        acc_o += fmaxf(cv[g][2] - tau, 0.f) * (float)vb[(size_t)j2 * 64];
        acc_o += fmaxf(cv[g][3] - tau, 0.f) * (float)vb[(size_t)j3 * 64];
      }
    } else {
      // mid path (33..64): 1 cand/lane butterfly Michelot + ballot-shfl gather
      float v = candv[wid][lane];
      int jv = candj[wid][lane];
      bool valid = lane < total;
      float cprev = -1.0f;
      for (int it = 0; it < 24; ++it) {
        bool in = valid && (v > tau);
        float s = in ? v : 0.f, c = in ? 1.f : 0.f;
#pragma unroll
        for (int o = 32; o; o >>= 1) { s += __shfl_xor(s, o); c += __shfl_xor(c, o); }
        if (c == cprev) break;
        tau = (s - 1.0f) / c; cprev = c;
      }
      float p = valid ? v - tau : 0.f;
      unsigned long long m = __ballot(p > 0.f);
      while (m) {
        int src = __ffsll((long long)m) - 1;
        m &= m - 1;
        float pj = __shfl(p, src);
        int j = __shfl(jv, src);
        acc_o += pj * (float)Vp[(size_t)j * 64 + lane];
      }
    }
  } else {
    // fallback (rare): read full row, full-register Michelot from tau0 + ballot gather
    h8 zc[4];
#pragma unroll
    for (int r = 0; r < 4; ++r)
      zc[r] = *(const h8*)&Srow[r * 512 + lane * 8];
    float cprev = -1.0f;
    for (int it = 0; it < 48; ++it) {
      float s = 0.f, c = 0.f;
#pragma unroll
      for (int r = 0; r < 4; ++r)
#pragma unroll
        for (int i = 0; i < 8; ++i) {
          float zz = (float)zc[r][i];
          if (zz > tau) { s += zz; c += 1.f; }
        }
#pragma unroll
      for (int o = 32; o; o >>= 1) { s += __shfl_xor(s, o); c += __shfl_xor(c, o); }
      if (c == cprev) break;
      tau = (s - 1.0f) / c; cprev = c;
    }
#pragma unroll
    for (int r = 0; r < 4; ++r)
#pragma unroll
      for (int i = 0; i < 8; ++i) {
        float p = (float)zc[r][i] - tau;
        unsigned long long m = __ballot(p > 0.f);
        while (m) {
          int src = __ffsll((long long)m) - 1;
          m &= m - 1;
          float pj = __shfl(p, src);
          int j = r * 512 + src * 8 + i;
          acc_o += pj * (float)Vp[(size_t)j * 64 + lane];
        }
      }
  }
  int rowg = (bh >> 3) * 2048 + n;          // [B][N] row
  AO[(size_t)rowg * 512 + (bh & 7) * 64 + lane] = (__bf16)acc_o;
}

// ---------------- kernel 3: out = AO @ W_out + b_out.  128x128 tile, T14 pipeline ----
__global__ __launch_bounds__(256) void out_gemm(
    const __bf16* __restrict__ A, const __bf16* __restrict__ wot,
    const float* __restrict__ bias, float* __restrict__ out) {
  __shared__ __bf16 Asm[128 * 64];
  __shared__ __bf16 Bsm[128 * 64];
  int bid = blockIdx.x;
  int bn = bid & 3, bm = bid >> 2;          // 4 col-tiles x 32 row-tiles of 128
  int t = threadIdx.x, lane = t & 63, wid = t >> 6;
  int wy = wid >> 1, wx = wid & 1;
  int l15 = lane & 15, lg = lane >> 4;
  int sr = t >> 3, sc = t & 7;
  const __bf16* Ag = A   + (size_t)(bm * 128 + sr) * 512 + sc * 8;
  const __bf16* Bg = wot + (size_t)(bn * 128 + sr) * 512 + sc * 8;
  int swz = (sc * 16) ^ ((sr & 7) << 4);
  bf8 ra[4], rb[4];
#pragma unroll
  for (int j = 0; j < 4; ++j) {
    ra[j] = *(const bf8*)(Ag + (size_t)(j * 32) * 512);
    rb[j] = *(const bf8*)(Bg + (size_t)(j * 32) * 512);
  }
  f4 acc[4][4];
#pragma unroll
  for (int mt = 0; mt < 4; ++mt)
#pragma unroll
    for (int nt = 0; nt < 4; ++nt) acc[mt][nt] = (f4){0.f, 0.f, 0.f, 0.f};

  for (int ks = 0; ks < 8; ++ks) {
    __syncthreads();
#pragma unroll
    for (int j = 0; j < 4; ++j) {
      *(bf8*)((char*)Asm + (size_t)(j * 32 + sr) * 128 + swz) = ra[j];
      *(bf8*)((char*)Bsm + (size_t)(j * 32 + sr) * 128 + swz) = rb[j];
    }
    if (ks < 7) {
      const __bf16* Ag2 = Ag + (ks + 1) * 64;
      const __bf16* Bg2 = Bg + (ks + 1) * 64;
#pragma unroll
      for (int j = 0; j < 4; ++j) {
        ra[j] = *(const bf8*)(Ag2 + (size_t)(j * 32) * 512);
        rb[j] = *(const bf8*)(Bg2 + (size_t)(j * 32) * 512);
      }
    }
    __syncthreads();
#pragma unroll
    for (int kk = 0; kk < 2; ++kk) {
      bf8 af[4], bg[4];
#pragma unroll
      for (int mt = 0; mt < 4; ++mt) {
        int r = wy * 64 + mt * 16 + l15;
        af[mt] = *(const bf8*)((const char*)Asm + (size_t)r * 128 +
                               ((kk * 64 + lg * 16) ^ ((r & 7) << 4)));
      }
#pragma unroll
      for (int nt = 0; nt < 4; ++nt) {
        int r = wx * 64 + nt * 16 + l15;
        bg[nt] = *(const bf8*)((const char*)Bsm + (size_t)r * 128 +
                               ((kk * 64 + lg * 16) ^ ((r & 7) << 4)));
      }
#pragma unroll
      for (int mt = 0; mt < 4; ++mt)
#pragma unroll
        for (int nt = 0; nt < 4; ++nt)
          acc[mt][nt] = __builtin_amdgcn_mfma_f32_16x16x32_bf16(af[mt], bg[nt], acc[mt][nt], 0, 0, 0);
    }
  }
#pragma unroll
  for (int mt = 0; mt < 4; ++mt)
#pragma unroll
    for (int nt = 0; nt < 4; ++nt) {
      int col = bn * 128 + wx * 64 + nt * 16 + l15;
      float bv = bias[col];
#pragma unroll
      for (int i = 0; i < 4; ++i) {
        int row = bm * 128 + wy * 64 + mt * 16 + lg * 4 + i;
        out[(size_t)row * 512 + col] = acc[mt][nt][i] + bv;
      }
    }
}

extern "C" void kernel_launch(void* const* d_in, const int* in_sizes, int n_in,
                              void* d_out, int out_size, void* d_ws, size_t ws_size,
                              hipStream_t stream) {
  const float* x  = (const float*)d_in[0];
  const float* Wq = (const float*)d_in[1];
  const float* Wo = (const float*)d_in[2];
  const float* bo = (const float*)d_in[3];
  char* ws = (char*)d_ws;
  __bf16* xb  = (__bf16*)(ws + XB_OFF);
  __bf16* wqt = (__bf16*)(ws + WQT_OFF);
  __bf16* wot = (__bf16*)(ws + WOT_OFF);
  __bf16* Qh  = (__bf16*)(ws + Q_OFF);
  __bf16* Kh  = (__bf16*)(ws + K_OFF);
  __bf16* Vh  = (__bf16*)(ws + V_OFF);
  __bf16* AO  = (__bf16*)(ws + AO_OFF);
  _Float16* Sg = (_Float16*)(ws + SG_OFF);
  float* bm = (float*)(ws + BM_OFF);

  prep_kernel<<<(ROWS * DIM) / 256, 256, 0, stream>>>(x, Wq, Wo, xb, wqt, wot);
  qkv_gemm<<<32 * 12, 256, 0, stream>>>(xb, wqt, Qh, Kh, Vh);
  qk_gemm<<<4096, 256, 0, stream>>>(Qh, Kh, Sg, bm);
  sparse_pv<<<4096, 512, 0, stream>>>(Sg, bm, Vh, AO);
  out_gemm<<<128, 256, 0, stream>>>(AO, wot, bo, (float*)d_out);
}

// Round 18
// 102.007 us; speedup vs baseline: 3.1260x; 1.3061x over previous
//
#include <hip/hip_runtime.h>

typedef __bf16 bf8 __attribute__((ext_vector_type(8)));
typedef float f4 __attribute__((ext_vector_type(4)));
typedef _Float16 h8 __attribute__((ext_vector_type(8)));
typedef _Float16 h2 __attribute__((ext_vector_type(2)));

// Problem constants (fixed by reference)
constexpr int BSZ = 2, NSEQ = 2048, DIM = 512, NH = 8, DH = 64, INNER = 512;
constexpr int ROWS = BSZ * NSEQ;          // 4096

// Workspace layout (bytes) — d_ws is >=268 MB (harness poison size)
constexpr size_t XB_OFF  = 0;                          // x cast bf16: 4 MB
constexpr size_t WQT_OFF = 4194304;                    // W_qkv^T bf16: 1.5 MB
constexpr size_t WOT_OFF = WQT_OFF + 1572864;          // W_out^T bf16: 0.5 MB
constexpr size_t Q_OFF   = WOT_OFF + 524288;           // Q/8 bf16 [16][2048][64]: 4 MB
constexpr size_t K_OFF   = Q_OFF + 4194304;            // K bf16: 4 MB
constexpr size_t V_OFF   = K_OFF + 4194304;            // V bf16: 4 MB
constexpr size_t AO_OFF  = V_OFF + 4194304;            // attn out bf16 [4096][512]: 4 MB
constexpr size_t SG_OFF  = AO_OFF + 4194304;           // S f16 [16][2048][2048]: 128 MB
constexpr size_t BM_OFF  = SG_OFF + 134217728;         // bmax f32 [16][2048][16]: 2 MB
// total ~152 MB

// ---------------- prep: cast x to bf16; transpose+cast W_qkv, W_out ----------------
__global__ __launch_bounds__(256) void prep_kernel(
    const float* __restrict__ x, const float* __restrict__ Wq, const float* __restrict__ Wo,
    __bf16* __restrict__ xb, __bf16* __restrict__ wqt, __bf16* __restrict__ wot) {
  int idx = blockIdx.x * 256 + threadIdx.x;
  if (idx < ROWS * DIM) xb[idx] = (__bf16)x[idx];
  if (idx < 3 * INNER * DIM) {            // wqt[n][k] = Wq[k][n]
    int n = idx >> 9, k = idx & 511;
    wqt[idx] = (__bf16)Wq[k * (3 * INNER) + n];
  }
  if (idx < INNER * DIM) {                // wot[n][k] = Wo[k][n]
    int n = idx >> 9, k = idx & 511;
    wot[idx] = (__bf16)Wo[k * DIM + n];
  }
}

// ---------------- kernel 1: qkv = x @ W_qkv -> Q/8,K,V.  128x128 tile, BK=64, ----
// T14 reg-staged LDS pipeline: issue loads for step k+1 before computing step k.
__global__ __launch_bounds__(256) void qkv_gemm(
    const __bf16* __restrict__ xb, const __bf16* __restrict__ wqt,
    __bf16* __restrict__ Qh, __bf16* __restrict__ Kh, __bf16* __restrict__ Vh) {
  __shared__ __bf16 Asm[128 * 64];          // byte = r*128 + (chbyte ^ ((r&7)<<4))
  __shared__ __bf16 Bsm[128 * 64];
  int bid = blockIdx.x;
  int bn = bid % 12, bm = bid / 12;         // 12 col-tiles x 32 row-tiles of 128
  int t = threadIdx.x, lane = t & 63, wid = t >> 6;
  int wy = wid >> 1, wx = wid & 1;
  int l15 = lane & 15, lg = lane >> 4;
  // staging geometry: thread t covers rows j*32+(t>>3), 16B chunk (t&7)
  int sr = t >> 3, sc = t & 7;
  const __bf16* Ag = xb  + (size_t)(bm * 128 + sr) * 512 + sc * 8;
  const __bf16* Bg = wqt + (size_t)(bn * 128 + sr) * 512 + sc * 8;
  int swz = (sc * 16) ^ ((sr & 7) << 4);    // (j*32 preserves r&7)
  bf8 ra[4], rb[4];
#pragma unroll
  for (int j = 0; j < 4; ++j) {
    ra[j] = *(const bf8*)(Ag + (size_t)(j * 32) * 512);
    rb[j] = *(const bf8*)(Bg + (size_t)(j * 32) * 512);
  }
  f4 acc[4][4];
#pragma unroll
  for (int mt = 0; mt < 4; ++mt)
#pragma unroll
    for (int nt = 0; nt < 4; ++nt) acc[mt][nt] = (f4){0.f, 0.f, 0.f, 0.f};

  for (int ks = 0; ks < 8; ++ks) {
    __syncthreads();                        // all waves done reading previous tile
#pragma unroll
    for (int j = 0; j < 4; ++j) {
      *(bf8*)((char*)Asm + (size_t)(j * 32 + sr) * 128 + swz) = ra[j];
      *(bf8*)((char*)Bsm + (size_t)(j * 32 + sr) * 128 + swz) = rb[j];
    }
    if (ks < 7) {                           // issue next-tile loads; they fly during MFMA
      const __bf16* Ag2 = Ag + (ks + 1) * 64;
      const __bf16* Bg2 = Bg + (ks + 1) * 64;
#pragma unroll
      for (int j = 0; j < 4; ++j) {
        ra[j] = *(const bf8*)(Ag2 + (size_t)(j * 32) * 512);
        rb[j] = *(const bf8*)(Bg2 + (size_t)(j * 32) * 512);
      }
    }
    __syncthreads();                        // LDS tile ready (lgkm drained)
#pragma unroll
    for (int kk = 0; kk < 2; ++kk) {
      bf8 af[4], bg[4];
#pragma unroll
      for (int mt = 0; mt < 4; ++mt) {
        int r = wy * 64 + mt * 16 + l15;
        af[mt] = *(const bf8*)((const char*)Asm + (size_t)r * 128 +
                               ((kk * 64 + lg * 16) ^ ((r & 7) << 4)));
      }
#pragma unroll
      for (int nt = 0; nt < 4; ++nt) {
        int r = wx * 64 + nt * 16 + l15;
        bg[nt] = *(const bf8*)((const char*)Bsm + (size_t)r * 128 +
                               ((kk * 64 + lg * 16) ^ ((r & 7) << 4)));
      }
#pragma unroll
      for (int mt = 0; mt < 4; ++mt)
#pragma unroll
        for (int nt = 0; nt < 4; ++nt)
          acc[mt][nt] = __builtin_amdgcn_mfma_f32_16x16x32_bf16(af[mt], bg[nt], acc[mt][nt], 0, 0, 0);
    }
  }
  // epilogue: scatter into Q/8, K, V
#pragma unroll
  for (int mt = 0; mt < 4; ++mt)
#pragma unroll
    for (int nt = 0; nt < 4; ++nt) {
      int col = bn * 128 + wx * 64 + nt * 16 + l15;
      int which = col >> 9;                  // 0=q 1=k 2=v
      int inner = col & 511;
      int h = inner >> 6, d = inner & 63;
      __bf16* dst = which == 0 ? Qh : (which == 1 ? Kh : Vh);
      float scale = which == 0 ? 0.125f : 1.0f;
#pragma unroll
      for (int i = 0; i < 4; ++i) {
        int row = bm * 128 + wy * 64 + mt * 16 + lg * 4 + i;
        int b = row >> 11, n = row & 2047;
        dst[(((size_t)(b * 8 + h)) * 2048 + n) * 64 + d] = (__bf16)(acc[mt][nt][i] * scale);
      }
    }
}

// ---------------- kernel 2a: S = (Q/8) @ K^T + per-block row-max, all 16 heads ----
// K-tile LDS-staged once per block (shared by 4 waves); LDS reused for store repack.
// Grid 4096, XCD-swizzled so each XCD works on ~2 heads (K/Q panels stay in its L2).
__global__ __launch_bounds__(256) void qk_gemm(
    const __bf16* __restrict__ Qh, const __bf16* __restrict__ Kh,
    _Float16* __restrict__ Sg, float* __restrict__ bmax) {
  __shared__ char lds[32768];               // [0,16K): K-tile; later: ct[4][32][128]
  int bid = blockIdx.x;
  int lin = (bid & 7) * 512 + (bid >> 3);   // bijective XCD swizzle (4096 % 8 == 0)
  int bh = lin >> 8;                        // head 0..15
  int rt = (lin >> 4) & 15;                 // q row-tile (128)
  int colt = lin & 15;                      // k col-tile (128)
  int t = threadIdx.x, lane = t & 63, wid = t >> 6;
  int l15 = lane & 15, lg = lane >> 4;

  // stage K-tile [128 rows][64 dims] cooperatively, swizzled (rule #21 both-sides)
  {
    int sr = t >> 3, sc = t & 7;            // 32 rows/pass, full 128B rows coalesced
    const __bf16* Kg = Kh + ((size_t)bh * 2048 + colt * 128 + sr) * 64 + sc * 8;
    bf8 k0 = *(const bf8*)(Kg);
    bf8 k1 = *(const bf8*)(Kg + 32 * 64);
    bf8 k2 = *(const bf8*)(Kg + 64 * 64);
    bf8 k3 = *(const bf8*)(Kg + 96 * 64);
    int swz = (sc * 16) ^ ((sr & 7) << 4);  // +32j preserves r&7
    *(bf8*)(lds + (size_t)sr * 128 + swz) = k0;
    *(bf8*)(lds + (size_t)(sr + 32) * 128 + swz) = k1;
    *(bf8*)(lds + (size_t)(sr + 64) * 128 + swz) = k2;
    *(bf8*)(lds + (size_t)(sr + 96) * 128 + swz) = k3;
  }
  const __bf16* Qp = Qh + ((size_t)bh * 2048 + rt * 128 + wid * 32) * 64;
  bf8 aA0 = *(const bf8*)(Qp + l15 * 64 + lg * 8);
  bf8 aA1 = *(const bf8*)(Qp + l15 * 64 + 32 + lg * 8);
  bf8 aB0 = *(const bf8*)(Qp + (16 + l15) * 64 + lg * 8);
  bf8 aB1 = *(const bf8*)(Qp + (16 + l15) * 64 + 32 + lg * 8);
  __syncthreads();                          // K-tile ready

  f4 acc[2][8];
#pragma unroll
  for (int s = 0; s < 2; ++s)
#pragma unroll
    for (int j = 0; j < 8; ++j) acc[s][j] = (f4){0.f, 0.f, 0.f, 0.f};
#pragma unroll
  for (int ctj = 0; ctj < 8; ++ctj) {
    int r = ctj * 16 + l15;
    const char* kb = lds + (size_t)r * 128;
    int sw = (r & 7) << 4;
    bf8 b0 = *(const bf8*)(kb + ((lg * 16) ^ sw));        // dims lg*8..+8
    bf8 b1 = *(const bf8*)(kb + ((64 + lg * 16) ^ sw));   // dims 32+lg*8..+8
    acc[0][ctj] = __builtin_amdgcn_mfma_f32_16x16x32_bf16(aA0, b0, acc[0][ctj], 0, 0, 0);
    acc[0][ctj] = __builtin_amdgcn_mfma_f32_16x16x32_bf16(aA1, b1, acc[0][ctj], 0, 0, 0);
    acc[1][ctj] = __builtin_amdgcn_mfma_f32_16x16x32_bf16(aB0, b0, acc[1][ctj], 0, 0, 0);
    acc[1][ctj] = __builtin_amdgcn_mfma_f32_16x16x32_bf16(aB1, b1, acc[1][ctj], 0, 0, 0);
  }
  // per-block row-max (for sparse_pv's filter)
#pragma unroll
  for (int s = 0; s < 2; ++s)
#pragma unroll
    for (int i = 0; i < 4; ++i) {
      float rm = acc[s][0][i];
#pragma unroll
      for (int ctj = 1; ctj < 8; ++ctj) rm = fmaxf(rm, acc[s][ctj][i]);
#pragma unroll
      for (int o = 1; o < 16; o <<= 1) rm = fmaxf(rm, __shfl_xor(rm, o));
      if (l15 == 0) {
        int row = rt * 128 + wid * 32 + s * 16 + lg * 4 + i;
        bmax[((size_t)bh * 2048 + row) * 16 + colt] = rm;
      }
    }
  __syncthreads();                          // all waves done reading K-tile; reuse LDS
  _Float16 (*ct)[32][128] = (_Float16(*)[32][128])lds;
#pragma unroll
  for (int s = 0; s < 2; ++s)
#pragma unroll
    for (int ctj = 0; ctj < 8; ++ctj)
#pragma unroll
      for (int i = 0; i < 4; ++i) {
        int row = s * 16 + lg * 4 + i;
        int col = ctj * 16 + l15;
        ct[wid][row][col ^ (((row >> 2) & 3) << 4)] = (_Float16)acc[s][ctj][i];
      }
  int r4 = lane >> 4, ch = lane & 15;       // wave-private region: no barrier needed
  size_t srow0 = (size_t)bh * 2048 + rt * 128 + wid * 32;
#pragma unroll
  for (int it = 0; it < 8; ++it) {
    int r = it * 4 + r4;
    h8 v = *(const h8*)&ct[wid][r][(ch * 8) ^ (((r >> 2) & 3) << 4)];
    *(h8*)&Sg[(srow0 + r) * 2048 + colt * 128 + ch * 8] = v;
  }
}

// ---------------- kernel 2b: bmax-filtered sparsemax + sparse PV, one wave/row ----
// Tight tau bound via Michelot on block maxima; ballot compaction; group-skip gather.
__global__ __launch_bounds__(512, 8) void sparse_pv(
    const _Float16* __restrict__ Sg, const float* __restrict__ bmax,
    const __bf16* __restrict__ Vh, __bf16* __restrict__ AO) {
  __shared__ float candv[8][64];            // 2 KB
  __shared__ int   candj[8][64];            // 2 KB
  int lane = threadIdx.x & 63, wid = threadIdx.x >> 6;   // 8 waves
  int rowid = blockIdx.x * 8 + wid;         // 0..32767
  int bh = rowid >> 11, n = rowid & 2047;
  const _Float16* Srow = Sg + ((size_t)bh * 2048 + n) * 2048;
  const float* bmr = bmax + ((size_t)bh * 2048 + n) * 16;
  const __bf16* Vp = Vh + (size_t)bh * 2048 * 64;

  float bmv[16];
  *(f4*)&bmv[0]  = *(const f4*)&bmr[0];
  *(f4*)&bmv[4]  = *(const f4*)&bmr[4];
  *(f4*)&bmv[8]  = *(const f4*)&bmr[8];
  *(f4*)&bmv[12] = *(const f4*)&bmr[12];
  float gmax = bmv[0];
#pragma unroll
  for (int ct = 1; ct < 16; ++ct) gmax = fmaxf(gmax, bmv[ct]);

  // Tight lower bound on tau*: Michelot on the 16 block maxima (each is a real,
  // distinct row element => f_sub(t) <= f(t) => tau_sub <= tau*). Iterates from a
  // lower bound remain lower bounds, so a FIXED 3 iterations is valid.
  float tlb = gmax - 1.0f;                  // k=1 bound (gmax block always active)
#pragma unroll
  for (int it = 0; it < 3; ++it) {
    float s = 0.f, c = 0.f;
#pragma unroll
    for (int ct = 0; ct < 16; ++ct) {
      float v = bmv[ct];
      if (v > tlb) { s += v; c += 1.f; }
    }
    tlb = (s - 1.0f) / c;                   // c >= 1 always (see bound above)
  }
  // slack: bmax is f32 but S is f16-rounded (ulp ~0.002 at |z|~4; averaged bound
  // overshoot <= ~0.002). 0.012 is 5x margin.
  float tau0 = tlb - 0.012f;

  candv[wid][lane] = -1e30f;                // prefill so unwritten slots are inert
  candj[wid][lane] = 0;
  unsigned long long lmask = (1ULL << lane) - 1;   // lower-lane mask
  int base = 0; bool ovf = false;
#pragma unroll
  for (int ct = 0; ct < 16; ++ct) {
    if (bmv[ct] > tau0) {                   // row-uniform -> wave-uniform
      h2 zz = *(const h2*)&Srow[ct * 128 + lane * 2];
      float z0 = (float)zz[0], z1 = (float)zz[1];
      bool c0 = z0 > tau0, c1 = z1 > tau0;
      unsigned long long b0 = __ballot(c0), b1 = __ballot(c1);
      int n0 = __popcll(b0);
      int tot = n0 + __popcll(b1);
      if (base + tot <= 64) {
        if (c0) {
          int s0 = base + __popcll(b0 & lmask);
          candv[wid][s0] = z0; candj[wid][s0] = ct * 128 + lane * 2;
        }
        if (c1) {
          int s1 = base + n0 + __popcll(b1 & lmask);
          candv[wid][s1] = z1; candj[wid][s1] = ct * 128 + lane * 2 + 1;
        }
      } else ovf = true;
      base += tot;
    }
  }
  int total = base;
  float tau = tau0, acc_o = 0.f;
  if (!ovf) {
    if (total <= 32) {
      // register path: group-skipped broadcast loads, pure-VALU Michelot, gather
      f4 cv[8];
#pragma unroll
      for (int g = 0; g < 8; ++g)
        cv[g] = (g * 4 < total) ? *(const f4*)&candv[wid][g * 4]
                                : (f4){-1e30f, -1e30f, -1e30f, -1e30f};
      float cprev = -1.0f;
      for (int it = 0; it < 12; ++it) {
        float s = 0.f, c = 0.f;
#pragma unroll
        for (int g = 0; g < 8; ++g) {
          if (g * 4 < total) {              // wave-uniform
#pragma unroll
            for (int i = 0; i < 4; ++i) {
              float v = cv[g][i];
              if (v > tau) { s += v; c += 1.f; }
            }
          }
        }
        if (c == cprev) break;
        tau = (s - 1.0f) / c; cprev = c;
      }
      // gather: dead slots (candj=0) hit V row 0 -> L1 broadcast, p<=0 contributes 0
      const __bf16* vb = Vp + lane;
#pragma unroll
      for (int g = 0; g < 8; ++g) {
        if (g * 4 < total) {                // wave-uniform
          int j0 = candj[wid][g * 4 + 0];
          int j1 = candj[wid][g * 4 + 1];
          int j2 = candj[wid][g * 4 + 2];
          int j3 = candj[wid][g * 4 + 3];
          acc_o += fmaxf(cv[g][0] - tau, 0.f) * (float)vb[(size_t)j0 * 64];
          acc_o += fmaxf(cv[g][1] - tau, 0.f) * (float)vb[(size_t)j1 * 64];
          acc_o += fmaxf(cv[g][2] - tau, 0.f) * (float)vb[(size_t)j2 * 64];
          acc_o += fmaxf(cv[g][3] - tau, 0.f) * (float)vb[(size_t)j3 * 64];
        }
      }
    } else {
      // mid path (33..64): 1 cand/lane butterfly Michelot + ballot-shfl gather
      float v = candv[wid][lane];
      int jv = candj[wid][lane];
      bool valid = lane < total;
      float cprev = -1.0f;
      for (int it = 0; it < 24; ++it) {
        bool in = valid && (v > tau);
        float s = in ? v : 0.f, c = in ? 1.f : 0.f;
#pragma unroll
        for (int o = 32; o; o >>= 1) { s += __shfl_xor(s, o); c += __shfl_xor(c, o); }
        if (c == cprev) break;
        tau = (s - 1.0f) / c; cprev = c;
      }
      float p = valid ? v - tau : 0.f;
      unsigned long long m = __ballot(p > 0.f);
      while (m) {
        int src = __ffsll((long long)m) - 1;
        m &= m - 1;
        float pj = __shfl(p, src);
        int j = __shfl(jv, src);
        acc_o += pj * (float)Vp[(size_t)j * 64 + lane];
      }
    }
  } else {
    // fallback (rare): read full row, full-register Michelot from tau0 + ballot gather
    h8 zc[4];
#pragma unroll
    for (int r = 0; r < 4; ++r)
      zc[r] = *(const h8*)&Srow[r * 512 + lane * 8];
    float cprev = -1.0f;
    for (int it = 0; it < 48; ++it) {
      float s = 0.f, c = 0.f;
#pragma unroll
      for (int r = 0; r < 4; ++r)
#pragma unroll
        for (int i = 0; i < 8; ++i) {
          float zz = (float)zc[r][i];
          if (zz > tau) { s += zz; c += 1.f; }
        }
#pragma unroll
      for (int o = 32; o; o >>= 1) { s += __shfl_xor(s, o); c += __shfl_xor(c, o); }
      if (c == cprev) break;
      tau = (s - 1.0f) / c; cprev = c;
    }
#pragma unroll
    for (int r = 0; r < 4; ++r)
#pragma unroll
      for (int i = 0; i < 8; ++i) {
        float p = (float)zc[r][i] - tau;
        unsigned long long m = __ballot(p > 0.f);
        while (m) {
          int src = __ffsll((long long)m) - 1;
          m &= m - 1;
          float pj = __shfl(p, src);
          int j = r * 512 + src * 8 + i;
          acc_o += pj * (float)Vp[(size_t)j * 64 + lane];
        }
      }
  }
  int rowg = (bh >> 3) * 2048 + n;          // [B][N] row
  AO[(size_t)rowg * 512 + (bh & 7) * 64 + lane] = (__bf16)acc_o;
}

// ---------------- kernel 3: out = AO @ W_out + b_out.  128x128 tile, T14 pipeline ----
__global__ __launch_bounds__(256) void out_gemm(
    const __bf16* __restrict__ A, const __bf16* __restrict__ wot,
    const float* __restrict__ bias, float* __restrict__ out) {
  __shared__ __bf16 Asm[128 * 64];
  __shared__ __bf16 Bsm[128 * 64];
  int bid = blockIdx.x;
  int bn = bid & 3, bm = bid >> 2;          // 4 col-tiles x 32 row-tiles of 128
  int t = threadIdx.x, lane = t & 63, wid = t >> 6;
  int wy = wid >> 1, wx = wid & 1;
  int l15 = lane & 15, lg = lane >> 4;
  int sr = t >> 3, sc = t & 7;
  const __bf16* Ag = A   + (size_t)(bm * 128 + sr) * 512 + sc * 8;
  const __bf16* Bg = wot + (size_t)(bn * 128 + sr) * 512 + sc * 8;
  int swz = (sc * 16) ^ ((sr & 7) << 4);
  bf8 ra[4], rb[4];
#pragma unroll
  for (int j = 0; j < 4; ++j) {
    ra[j] = *(const bf8*)(Ag + (size_t)(j * 32) * 512);
    rb[j] = *(const bf8*)(Bg + (size_t)(j * 32) * 512);
  }
  f4 acc[4][4];
#pragma unroll
  for (int mt = 0; mt < 4; ++mt)
#pragma unroll
    for (int nt = 0; nt < 4; ++nt) acc[mt][nt] = (f4){0.f, 0.f, 0.f, 0.f};

  for (int ks = 0; ks < 8; ++ks) {
    __syncthreads();
#pragma unroll
    for (int j = 0; j < 4; ++j) {
      *(bf8*)((char*)Asm + (size_t)(j * 32 + sr) * 128 + swz) = ra[j];
      *(bf8*)((char*)Bsm + (size_t)(j * 32 + sr) * 128 + swz) = rb[j];
    }
    if (ks < 7) {
      const __bf16* Ag2 = Ag + (ks + 1) * 64;
      const __bf16* Bg2 = Bg + (ks + 1) * 64;
#pragma unroll
      for (int j = 0; j < 4; ++j) {
        ra[j] = *(const bf8*)(Ag2 + (size_t)(j * 32) * 512);
        rb[j] = *(const bf8*)(Bg2 + (size_t)(j * 32) * 512);
      }
    }
    __syncthreads();
#pragma unroll
    for (int kk = 0; kk < 2; ++kk) {
      bf8 af[4], bg[4];
#pragma unroll
      for (int mt = 0; mt < 4; ++mt) {
        int r = wy * 64 + mt * 16 + l15;
        af[mt] = *(const bf8*)((const char*)Asm + (size_t)r * 128 +
                               ((kk * 64 + lg * 16) ^ ((r & 7) << 4)));
      }
#pragma unroll
      for (int nt = 0; nt < 4; ++nt) {
        int r = wx * 64 + nt * 16 + l15;
        bg[nt] = *(const bf8*)((const char*)Bsm + (size_t)r * 128 +
                               ((kk * 64 + lg * 16) ^ ((r & 7) << 4)));
      }
#pragma unroll
      for (int mt = 0; mt < 4; ++mt)
#pragma unroll
        for (int nt = 0; nt < 4; ++nt)
          acc[mt][nt] = __builtin_amdgcn_mfma_f32_16x16x32_bf16(af[mt], bg[nt], acc[mt][nt], 0, 0, 0);
    }
  }
#pragma unroll
  for (int mt = 0; mt < 4; ++mt)
#pragma unroll
    for (int nt = 0; nt < 4; ++nt) {
      int col = bn * 128 + wx * 64 + nt * 16 + l15;
      float bv = bias[col];
#pragma unroll
      for (int i = 0; i < 4; ++i) {
        int row = bm * 128 + wy * 64 + mt * 16 + lg * 4 + i;
        out[(size_t)row * 512 + col] = acc[mt][nt][i] + bv;
      }
    }
}

extern "C" void kernel_launch(void* const* d_in, const int* in_sizes, int n_in,
                              void* d_out, int out_size, void* d_ws, size_t ws_size,
                              hipStream_t stream) {
  const float* x  = (const float*)d_in[0];
  const float* Wq = (const float*)d_in[1];
  const float* Wo = (const float*)d_in[2];
  const float* bo = (const float*)d_in[3];
  char* ws = (char*)d_ws;
  __bf16* xb  = (__bf16*)(ws + XB_OFF);
  __bf16* wqt = (__bf16*)(ws + WQT_OFF);
  __bf16* wot = (__bf16*)(ws + WOT_OFF);
  __bf16* Qh  = (__bf16*)(ws + Q_OFF);
  __bf16* Kh  = (__bf16*)(ws + K_OFF);
  __bf16* Vh  = (__bf16*)(ws + V_OFF);
  __bf16* AO  = (__bf16*)(ws + AO_OFF);
  _Float16* Sg = (_Float16*)(ws + SG_OFF);
  float* bm = (float*)(ws + BM_OFF);

  prep_kernel<<<(ROWS * DIM) / 256, 256, 0, stream>>>(x, Wq, Wo, xb, wqt, wot);
  qkv_gemm<<<32 * 12, 256, 0, stream>>>(xb, wqt, Qh, Kh, Vh);
  qk_gemm<<<4096, 256, 0, stream>>>(Qh, Kh, Sg, bm);
  sparse_pv<<<4096, 512, 0, stream>>>(Sg, bm, Vh, AO);
  out_gemm<<<128, 256, 0, stream>>>(AO, wot, bo, (float*)d_out);
}